// Round 5
// baseline (234.075 us; speedup 1.0000x reference)
//
#include <hip/hip_runtime.h>
#include <stdint.h>

typedef __attribute__((ext_vector_type(8))) short shortx8;
typedef __attribute__((ext_vector_type(4))) float floatx4;

static constexpr int SEQ_    = 2048;
static constexpr int DMODEL  = 1024;
static constexpr int HDIM    = 64;
static constexpr int BATCH_  = 2;
static constexpr int NHEADS  = 16;
static constexpr int WINDOW_ = 64;
static constexpr int GTOK    = 4;
static constexpr int RTOK    = 32;
static constexpr int ROWS    = BATCH_ * SEQ_;   // 4096
static constexpr int QKVN    = 3 * DMODEL;      // 3072

__device__ inline unsigned short f2bf(float f) {
  union { float f; unsigned int u; } x; x.f = f;
  unsigned int r = (x.u + 0x7FFFu + ((x.u >> 16) & 1u)) >> 16;
  return (unsigned short)r;
}
__device__ inline float bf2f(unsigned short b) {
  union { unsigned int u; float f; } x; x.u = ((unsigned int)b) << 16;
  return x.f;
}

__device__ inline void gload_lds16(const void* g, void* l) {
  __builtin_amdgcn_global_load_lds(
      (const __attribute__((address_space(1))) void*)g,
      (__attribute__((address_space(3))) void*)l, 16, 0, 0);
}

// ---------------- LayerNorm -> bf16 ----------------
__global__ __launch_bounds__(256) void ln_kernel(const float* __restrict__ x,
    const float* __restrict__ gamma, const float* __restrict__ beta,
    unsigned short* __restrict__ xn) {
  int row = blockIdx.x;
  int t = threadIdx.x;
  const float4* xr = (const float4*)(x + (size_t)row * DMODEL);
  float4 v = xr[t];
  float s = v.x + v.y + v.z + v.w;
  #pragma unroll
  for (int o = 32; o > 0; o >>= 1) s += __shfl_xor(s, o);
  __shared__ float red[4];
  __shared__ float red2[4];
  int wave = t >> 6, lane = t & 63;
  if (lane == 0) red[wave] = s;
  __syncthreads();
  float mean = (red[0] + red[1] + red[2] + red[3]) * (1.0f / DMODEL);
  float dx = v.x - mean, dy = v.y - mean, dz = v.z - mean, dw = v.w - mean;
  float q = dx*dx + dy*dy + dz*dz + dw*dw;
  #pragma unroll
  for (int o = 32; o > 0; o >>= 1) q += __shfl_xor(q, o);
  if (lane == 0) red2[wave] = q;
  __syncthreads();
  float var = (red2[0] + red2[1] + red2[2] + red2[3]) * (1.0f / DMODEL);
  float rs = rsqrtf(var + 1e-5f);
  float4 g = ((const float4*)gamma)[t];
  float4 bb = ((const float4*)beta)[t];
  ushort4 outv;
  outv.x = f2bf(dx * rs * g.x + bb.x);
  outv.y = f2bf(dy * rs * g.y + bb.y);
  outv.z = f2bf(dz * rs * g.z + bb.z);
  outv.w = f2bf(dw * rs * g.w + bb.w);
  ((ushort4*)(xn + (size_t)row * DMODEL))[t] = outv;
}

// ---------------- transpose + convert: src[K][N] fp32 -> dst[N][K] bf16 ----------------
__global__ __launch_bounds__(256) void cvtT_kernel(const float* __restrict__ src,
    unsigned short* __restrict__ dst, int K, int N) {
  __shared__ float tile[32][33];
  int k0 = blockIdx.y * 32, n0 = blockIdx.x * 32;
  int tx = threadIdx.x & 31, ty = threadIdx.x >> 5;  // 32x8
  #pragma unroll
  for (int r = ty; r < 32; r += 8)
    tile[r][tx] = src[(size_t)(k0 + r) * N + n0 + tx];
  __syncthreads();
  #pragma unroll
  for (int r = ty; r < 32; r += 8)
    dst[(size_t)(n0 + r) * K + k0 + tx] = f2bf(tile[tx][r]);
}

// ---------------- fused weight prep: z=0 cvtT(w_out)->woT ; z=1 plain cvt of Wv slice ---
__global__ __launch_bounds__(256) void cvt_fused(const float* __restrict__ w_out,
    const float* __restrict__ w_qkv, unsigned short* __restrict__ woT,
    unsigned short* __restrict__ Wvs) {
  __shared__ float tile[32][33];
  int k0 = blockIdx.y * 32, n0 = blockIdx.x * 32;
  int tx = threadIdx.x & 31, ty = threadIdx.x >> 5;
  if (blockIdx.z == 0) {
    #pragma unroll
    for (int r = ty; r < 32; r += 8)
      tile[r][tx] = w_out[(size_t)(k0 + r) * DMODEL + n0 + tx];
    __syncthreads();
    #pragma unroll
    for (int r = ty; r < 32; r += 8)
      woT[(size_t)(n0 + r) * DMODEL + k0 + tx] = f2bf(tile[tx][r]);
  } else {
    // Wvs[k][v] = w_qkv[k][2048+v]
    #pragma unroll
    for (int r = ty; r < 32; r += 8)
      Wvs[(size_t)(k0 + r) * DMODEL + n0 + tx] =
          f2bf(w_qkv[(size_t)(k0 + r) * QKVN + 2 * DMODEL + n0 + tx]);
  }
}

// ---------------- bf16 MFMA GEMM: C[M x N] = A[MxK] @ BT[NxK]^T (+resid) ------
__global__ __launch_bounds__(256) void gemm128x64(
    const unsigned short* __restrict__ A, const unsigned short* __restrict__ BT,
    unsigned short* __restrict__ Cb, float* __restrict__ Cf,
    const float* __restrict__ resid, int M, int N, int K, int ldc) {
  __shared__ unsigned short Al[128 * 32];
  __shared__ unsigned short Bl[64 * 32];
  const int bm = blockIdx.y * 128, bn = blockIdx.x * 64;
  const int tid = threadIdx.x;
  const int wave = tid >> 6, lane = tid & 63;
  const int wm = (wave >> 1) * 64, wn = (wave & 1) * 32;
  const int quad = lane >> 4, l16 = lane & 15;
  const int lrow = lane >> 2;          // 16 rows per chunk, 4 lanes/row
  const int lkoff = (lane & 3) * 8;    // 8 bf16 = 16B per lane
  floatx4 acc[4][2] = {};
  for (int k0 = 0; k0 < K; k0 += 32) {
    __syncthreads();
    #pragma unroll
    for (int q = 0; q < 2; q++) {       // A: 128 rows, wave stages 32
      int r = wave * 32 + q * 16;
      gload_lds16(A + (size_t)(bm + r + lrow) * K + k0 + lkoff, Al + r * 32);
    }
    {                                   // B: 64 rows, wave stages 16
      int r = wave * 16;
      gload_lds16(BT + (size_t)(bn + r + lrow) * K + k0 + lkoff, Bl + r * 32);
    }
    __syncthreads();
    shortx8 af[4], bfr[2];
    #pragma unroll
    for (int s = 0; s < 4; s++)
      af[s] = *(const shortx8*)&Al[(wm + s * 16 + l16) * 32 + quad * 8];
    #pragma unroll
    for (int s = 0; s < 2; s++)
      bfr[s] = *(const shortx8*)&Bl[(wn + s * 16 + l16) * 32 + quad * 8];
    #pragma unroll
    for (int sm = 0; sm < 4; sm++)
      #pragma unroll
      for (int sn = 0; sn < 2; sn++)
        acc[sm][sn] = __builtin_amdgcn_mfma_f32_16x16x32_bf16(af[sm], bfr[sn], acc[sm][sn], 0, 0, 0);
  }
  #pragma unroll
  for (int sm = 0; sm < 4; sm++)
    #pragma unroll
    for (int sn = 0; sn < 2; sn++)
      #pragma unroll
      for (int r = 0; r < 4; r++) {
        int row = bm + wm + sm * 16 + quad * 4 + r;
        int col = bn + wn + sn * 16 + l16;
        size_t off = (size_t)row * ldc + col;
        float v = acc[sm][sn][r];
        if (resid) v += resid[off];
        if (Cf) Cf[off] = v;
        else    Cb[off] = f2bf(v);
      }
}

// ---------------- per-row top-tier mask column lists ----------------
__global__ __launch_bounds__(64) void mask_rows(const int* __restrict__ rand_idx,
    int* __restrict__ cols, int* __restrict__ cnt, int* __restrict__ tmx) {
  const int i = blockIdx.x;
  const int lane = threadIdx.x;
  __shared__ int rl[RTOK];
  __shared__ int scount;
  if (lane < RTOK) rl[lane] = rand_idx[i * RTOK + lane];
  if (lane == 0) scount = 0;
  __syncthreads();
  const int wstart = (i - WINDOW_ > 0) ? (i - WINDOW_) : 0;
  int jj[2]; int tt[2];
  #pragma unroll
  for (int p = 0; p < 2; p++) {
    int c = lane + p * 64;
    int j = -1;
    bool valid = false;
    if (c < 65) {
      j = i - WINDOW_ + c;
      valid = (j >= 0);
    } else if (c < 73) {
      int g = c - 65;
      j = (g < 4) ? g : (SEQ_ - 8 + g);
      valid = (j <= i) && (j < wstart);
    } else if (c < 73 + RTOK) {
      int r = c - 73;
      j = rl[r];
      bool dup = false;
      for (int r2 = 0; r2 < r; r2++) dup = dup || (rl[r2] == j);
      valid = (j <= i) && (j < wstart) && !(j < GTOK || j >= SEQ_ - GTOK) && !dup;
    }
    int t = -1;
    if (valid) {
      int loc = ((i - j) <= WINDOW_) ? 1 : 0;
      int glb = (j < GTOK || j >= SEQ_ - GTOK) ? 1 : 0;
      int rnd = 0;
      for (int r = 0; r < RTOK; r++) rnd |= (rl[r] == j) ? 1 : 0;
      t = loc + glb + rnd;
    }
    jj[p] = j; tt[p] = t;
  }
  int tm = (tt[0] > tt[1]) ? tt[0] : tt[1];
  #pragma unroll
  for (int o = 1; o < 64; o <<= 1) {
    int other = __shfl_xor(tm, o);
    tm = (other > tm) ? other : tm;
  }
  #pragma unroll
  for (int p = 0; p < 2; p++) {
    if (tt[p] == tm) {
      int pos = atomicAdd(&scount, 1);
      cols[i * 128 + pos] = jj[p];
    }
  }
  __syncthreads();
  if (lane == 0) { cnt[i] = scount; tmx[i] = tm; }
}

// ---------------- build gather lists for tier-3 fixup ----------------
__global__ __launch_bounds__(256) void build_list(const int* __restrict__ tmx,
    int* __restrict__ qlist, int* __restrict__ klist) {
  const int t = threadIdx.x;
  qlist[t] = -1;
  if (t < 128) klist[t] = -1;
  __shared__ int nq;
  if (t == 0) nq = 0;
  __syncthreads();
  if (t < 144) {                      // 72 candidate rows x 2 batches
    int c = t >> 1, b = t & 1;
    int i = (c < 68) ? c : (2044 + (c - 68));
    if (tmx[i] == 3) {
      int slot = atomicAdd(&nq, 1);
      qlist[slot] = b * SEQ_ + i;
    }
  }
  if (t < 16) {                       // 8 global cols per batch
    int b = t >> 3, g = t & 7;
    int j = (g < 4) ? g : (2040 + g);
    klist[t] = b * SEQ_ + j;
  }
}

// ---------------- fused gather mini-GEMM: q (2 slabs), k, v ----------------
// buf[m][col] = xn[list[m]] @ BT ; pad rows (list<0) computed on row 0, stored (harmless).
__global__ __launch_bounds__(256) void gemm_gather3(
    const unsigned short* __restrict__ xn, const unsigned short* __restrict__ wqT,
    const int* __restrict__ qlist, const int* __restrict__ klist,
    unsigned short* __restrict__ qf, unsigned short* __restrict__ kf,
    unsigned short* __restrict__ vf) {
  const int job = blockIdx.y;
  const int* list; const unsigned short* BT; unsigned short* dstbuf;
  if (job < 2)      { list = qlist + job * 128; BT = wqT;                        dstbuf = qf + (size_t)job * 128 * DMODEL; }
  else if (job == 2){ list = klist;             BT = wqT + (size_t)DMODEL*DMODEL;  dstbuf = kf; }
  else              { list = klist;             BT = wqT + (size_t)2*DMODEL*DMODEL; dstbuf = vf; }
  __shared__ unsigned short Al[128 * 32];
  __shared__ unsigned short Bl[64 * 32];
  const int bn = blockIdx.x * 64;
  const int tid = threadIdx.x;
  const int wave = tid >> 6, lane = tid & 63;
  const int wm = (wave >> 1) * 64, wn = (wave & 1) * 32;
  const int quad = lane >> 4, l16 = lane & 15;
  const int lrow = lane >> 2;
  const int lkoff = (lane & 3) * 8;
  int rsrc[2];
  #pragma unroll
  for (int q = 0; q < 2; q++) {
    int s = list[wave * 32 + q * 16 + lrow];
    rsrc[q] = (s < 0) ? 0 : s;
  }
  floatx4 acc[4][2] = {};
  for (int k0 = 0; k0 < DMODEL; k0 += 32) {
    __syncthreads();
    #pragma unroll
    for (int q = 0; q < 2; q++) {
      int r = wave * 32 + q * 16;
      gload_lds16(xn + (size_t)rsrc[q] * DMODEL + k0 + lkoff, Al + r * 32);
    }
    {
      int r = wave * 16;
      gload_lds16(BT + (size_t)(bn + r + lrow) * DMODEL + k0 + lkoff, Bl + r * 32);
    }
    __syncthreads();
    shortx8 af[4], bfr[2];
    #pragma unroll
    for (int s = 0; s < 4; s++)
      af[s] = *(const shortx8*)&Al[(wm + s * 16 + l16) * 32 + quad * 8];
    #pragma unroll
    for (int s = 0; s < 2; s++)
      bfr[s] = *(const shortx8*)&Bl[(wn + s * 16 + l16) * 32 + quad * 8];
    #pragma unroll
    for (int sm = 0; sm < 4; sm++)
      #pragma unroll
      for (int sn = 0; sn < 2; sn++)
        acc[sm][sn] = __builtin_amdgcn_mfma_f32_16x16x32_bf16(af[sm], bfr[sn], acc[sm][sn], 0, 0, 0);
  }
  #pragma unroll
  for (int sm = 0; sm < 4; sm++)
    #pragma unroll
    for (int sn = 0; sn < 2; sn++)
      #pragma unroll
      for (int r = 0; r < 4; r++) {
        int row = wm + sm * 16 + quad * 4 + r;
        int col = bn + wn + sn * 16 + l16;
        dstbuf[(size_t)row * DMODEL + col] = f2bf(acc[sm][sn][r]);
      }
}

// ---------------- tier-3 per-head softmax -> vbar rows ----------------
__global__ __launch_bounds__(64) void attn_fix(
    const unsigned short* __restrict__ qf, const unsigned short* __restrict__ kf,
    const unsigned short* __restrict__ vf, const int* __restrict__ qlist,
    const int* __restrict__ cols, const int* __restrict__ cnt,
    unsigned short* __restrict__ vbar) {
  const int s = blockIdx.x;
  const int dst = qlist[s];
  if (dst < 0) return;
  const int b = dst >> 11, i = dst & 2047;
  const int n = cnt[i];
  const int lane = threadIdx.x;
  __shared__ int kss[8];
  if (lane < n) {
    int j = cols[i * 128 + lane];
    kss[lane] = b * 8 + ((j < 4) ? j : (j - 2040));
  }
  __syncthreads();
  for (int h = 0; h < NHEADS; h++) {
    float qd = bf2f(qf[(size_t)s * DMODEL + h * HDIM + lane]);
    float w[8];
    float m = -1e30f;
    for (int c = 0; c < n; c++) {
      float kd = bf2f(kf[(size_t)kss[c] * DMODEL + h * HDIM + lane]);
      float p = qd * kd;
      #pragma unroll
      for (int o = 32; o > 0; o >>= 1) p += __shfl_xor(p, o);
      p *= 0.375f;    // 3 * (qk/8)
      w[c] = p;
      m = fmaxf(m, p);
    }
    float denom = 0.f, acc = 0.f;
    for (int c = 0; c < n; c++) {
      float e = __expf(w[c] - m);
      denom += e;
      acc += e * bf2f(vf[(size_t)kss[c] * DMODEL + h * HDIM + lane]);
    }
    vbar[(size_t)s * DMODEL + h * HDIM + lane] = f2bf(acc / denom);
  }
}

// ---------------- xbar: mean of top-tier xn rows (R3-style loop) ----------------
__global__ __launch_bounds__(256) void xbar_kernel(
    const unsigned short* __restrict__ xn, const int* __restrict__ cols,
    const int* __restrict__ cnt, const int* __restrict__ tmx,
    unsigned short* __restrict__ xbar) {
  const int i = blockIdx.x, b = blockIdx.y;
  const int t = threadIdx.x;
  const int n = cnt[i], tm = tmx[i];
  __shared__ int cj[128];
  for (int c = t; c < n; c += 256) cj[c] = cols[i * 128 + c];
  __syncthreads();
  ushort4* dst = (ushort4*)(xbar + (size_t)(b * SEQ_ + i) * DMODEL);
  if (tm == 3) {            // handled by fix path; zero so main GEMM stays finite
    ushort4 z = {0, 0, 0, 0};
    dst[t] = z;
    return;
  }
  const ushort4* vb = (const ushort4*)(xn + (size_t)(b * SEQ_) * DMODEL); // row = 256 u4
  float4 s0 = {0,0,0,0}, s1 = {0,0,0,0}, s2 = {0,0,0,0}, s3 = {0,0,0,0};
  int c = 0;
  for (; c + 4 <= n; c += 4) {
    int j0 = cj[c], j1 = cj[c+1], j2 = cj[c+2], j3 = cj[c+3];
    ushort4 a0 = vb[(size_t)j0 * 256 + t];
    ushort4 a1 = vb[(size_t)j1 * 256 + t];
    ushort4 a2 = vb[(size_t)j2 * 256 + t];
    ushort4 a3 = vb[(size_t)j3 * 256 + t];
    s0.x += bf2f(a0.x); s0.y += bf2f(a0.y); s0.z += bf2f(a0.z); s0.w += bf2f(a0.w);
    s1.x += bf2f(a1.x); s1.y += bf2f(a1.y); s1.z += bf2f(a1.z); s1.w += bf2f(a1.w);
    s2.x += bf2f(a2.x); s2.y += bf2f(a2.y); s2.z += bf2f(a2.z); s2.w += bf2f(a2.w);
    s3.x += bf2f(a3.x); s3.y += bf2f(a3.y); s3.z += bf2f(a3.z); s3.w += bf2f(a3.w);
  }
  for (; c < n; c++) {
    ushort4 a0 = vb[(size_t)cj[c] * 256 + t];
    s0.x += bf2f(a0.x); s0.y += bf2f(a0.y); s0.z += bf2f(a0.z); s0.w += bf2f(a0.w);
  }
  float inv = 1.0f / (float)n;
  ushort4 o;
  o.x = f2bf((s0.x + s1.x + s2.x + s3.x) * inv);
  o.y = f2bf((s0.y + s1.y + s2.y + s3.y) * inv);
  o.z = f2bf((s0.z + s1.z + s2.z + s3.z) * inv);
  o.w = f2bf((s0.w + s1.w + s2.w + s3.w) * inv);
  dst[t] = o;
}

// ---------------- fix-out GEMM: out[qlist[m]] = vbar[m] @ woT^T + x[qlist[m]] ----------
__global__ __launch_bounds__(256) void gemm_fix(
    const unsigned short* __restrict__ vbar, const unsigned short* __restrict__ woT,
    const int* __restrict__ qlist, const float* __restrict__ x,
    float* __restrict__ out) {
  __shared__ unsigned short Al[128 * 32];
  __shared__ unsigned short Bl[64 * 32];
  __shared__ int sdst[128];
  const int bm = blockIdx.y * 128, bn = blockIdx.x * 64;
  const int tid = threadIdx.x;
  const int wave = tid >> 6, lane = tid & 63;
  const int wm = (wave >> 1) * 64, wn = (wave & 1) * 32;
  const int quad = lane >> 4, l16 = lane & 15;
  const int lrow = lane >> 2;
  const int lkoff = (lane & 3) * 8;
  if (tid < 128) sdst[tid] = qlist[bm + tid];
  floatx4 acc[4][2] = {};
  for (int k0 = 0; k0 < DMODEL; k0 += 32) {
    __syncthreads();
    #pragma unroll
    for (int q = 0; q < 2; q++) {
      int r = wave * 32 + q * 16;
      gload_lds16(vbar + (size_t)(bm + r + lrow) * DMODEL + k0 + lkoff, Al + r * 32);
    }
    {
      int r = wave * 16;
      gload_lds16(woT + (size_t)(bn + r + lrow) * DMODEL + k0 + lkoff, Bl + r * 32);
    }
    __syncthreads();
    shortx8 af[4], bfr[2];
    #pragma unroll
    for (int s = 0; s < 4; s++)
      af[s] = *(const shortx8*)&Al[(wm + s * 16 + l16) * 32 + quad * 8];
    #pragma unroll
    for (int s = 0; s < 2; s++)
      bfr[s] = *(const shortx8*)&Bl[(wn + s * 16 + l16) * 32 + quad * 8];
    #pragma unroll
    for (int sm = 0; sm < 4; sm++)
      #pragma unroll
      for (int sn = 0; sn < 2; sn++)
        acc[sm][sn] = __builtin_amdgcn_mfma_f32_16x16x32_bf16(af[sm], bfr[sn], acc[sm][sn], 0, 0, 0);
  }
  #pragma unroll
  for (int sm = 0; sm < 4; sm++)
    #pragma unroll
    for (int sn = 0; sn < 2; sn++)
      #pragma unroll
      for (int r = 0; r < 4; r++) {
        int dst = sdst[wm + sm * 16 + quad * 4 + r];
        if (dst >= 0) {
          int col = bn + wn + sn * 16 + l16;
          size_t off = (size_t)dst * DMODEL + col;
          out[off] = acc[sm][sn][r] + x[off];
        }
      }
}

extern "C" void kernel_launch(void* const* d_in, const int* in_sizes, int n_in,
                              void* d_out, int out_size, void* d_ws, size_t ws_size,
                              hipStream_t stream) {
  const float* x     = (const float*)d_in[0];
  const float* w_qkv = (const float*)d_in[1];
  const float* w_out = (const float*)d_in[2];
  const float* gamma = (const float*)d_in[3];
  const float* beta  = (const float*)d_in[4];
  const int*   ridx  = (const int*)d_in[5];
  float* out = (float*)d_out;

  char* ws = (char*)d_ws;
  size_t off = 0;
  auto alloc = [&](size_t bytes) {
    char* p = ws + off;
    off = (off + bytes + 255) & ~(size_t)255;
    return p;
  };
  unsigned short* xn   = (unsigned short*)alloc((size_t)ROWS * DMODEL * 2);     // 8 MB
  unsigned short* wqT  = (unsigned short*)alloc((size_t)QKVN * DMODEL * 2);     // 6 MB (N x K)
  unsigned short* woT  = (unsigned short*)alloc((size_t)DMODEL * DMODEL * 2);   // 2 MB (N x K)
  unsigned short* Wvs  = (unsigned short*)alloc((size_t)DMODEL * DMODEL * 2);   // 2 MB (K x V)
  unsigned short* WvoT = (unsigned short*)alloc((size_t)DMODEL * DMODEL * 2);   // 2 MB (N x K)
  unsigned short* xbar = (unsigned short*)alloc((size_t)ROWS * DMODEL * 2);     // 8 MB
  unsigned short* qf   = (unsigned short*)alloc((size_t)256 * DMODEL * 2);
  unsigned short* kf   = (unsigned short*)alloc((size_t)128 * DMODEL * 2);
  unsigned short* vf   = (unsigned short*)alloc((size_t)128 * DMODEL * 2);
  unsigned short* vbar = (unsigned short*)alloc((size_t)256 * DMODEL * 2);
  int* cols  = (int*)alloc((size_t)SEQ_ * 128 * 4);                             // 1 MB
  int* cnt   = (int*)alloc((size_t)SEQ_ * 4);
  int* tmx   = (int*)alloc((size_t)SEQ_ * 4);
  int* qlist = (int*)alloc(256 * 4);
  int* klist = (int*)alloc(128 * 4);

  hipLaunchKernelGGL(ln_kernel, dim3(ROWS), dim3(256), 0, stream, x, gamma, beta, xn);
  hipLaunchKernelGGL(cvtT_kernel, dim3(QKVN / 32, DMODEL / 32), dim3(256), 0, stream,
                     w_qkv, wqT, DMODEL, QKVN);
  hipLaunchKernelGGL(cvt_fused, dim3(DMODEL / 32, DMODEL / 32, 2), dim3(256), 0, stream,
                     w_out, w_qkv, woT, Wvs);
  hipLaunchKernelGGL(mask_rows, dim3(SEQ_), dim3(64), 0, stream, ridx, cols, cnt, tmx);
  hipLaunchKernelGGL(build_list, dim3(1), dim3(256), 0, stream, tmx, qlist, klist);
  // WvoT[n][k] = sum_v woT[n][v] * Wvs[k][v]  (i.e. Wvo = Wv @ Wo, stored transposed)
  hipLaunchKernelGGL(gemm128x64, dim3(DMODEL / 64, DMODEL / 128), dim3(256), 0, stream,
                     woT, Wvs, WvoT, (float*)nullptr, (const float*)nullptr,
                     DMODEL, DMODEL, DMODEL, DMODEL);
  // tier-3 gathers: q (2 slabs), k, v
  hipLaunchKernelGGL(gemm_gather3, dim3(DMODEL / 64, 4), dim3(256), 0, stream,
                     xn, wqT, qlist, klist, qf, kf, vf);
  hipLaunchKernelGGL(attn_fix, dim3(256), dim3(64), 0, stream,
                     qf, kf, vf, qlist, cols, cnt, vbar);
  hipLaunchKernelGGL(xbar_kernel, dim3(SEQ_, BATCH_), dim3(256), 0, stream,
                     xn, cols, cnt, tmx, xbar);
  // main fused GEMM: out = xbar @ Wvo + x
  hipLaunchKernelGGL(gemm128x64, dim3(DMODEL / 64, ROWS / 128), dim3(256), 0, stream,
                     xbar, WvoT, (unsigned short*)nullptr, out, x, ROWS, DMODEL, DMODEL, DMODEL);
  // overwrite tier-3 rows: out[dst] = vbar @ Wo + x[dst]
  hipLaunchKernelGGL(gemm_fix, dim3(DMODEL / 64, 2), dim3(256), 0, stream,
                     vbar, woT, qlist, x, out);
}

// Round 6
// 210.473 us; speedup vs baseline: 1.1121x; 1.1121x over previous
//
#include <hip/hip_runtime.h>
#include <stdint.h>

typedef __attribute__((ext_vector_type(8))) short shortx8;
typedef __attribute__((ext_vector_type(4))) float floatx4;

static constexpr int SEQ_    = 2048;
static constexpr int DMODEL  = 1024;
static constexpr int HDIM    = 64;
static constexpr int BATCH_  = 2;
static constexpr int NHEADS  = 16;
static constexpr int WINDOW_ = 64;
static constexpr int GTOK    = 4;
static constexpr int RTOK    = 32;
static constexpr int ROWS    = BATCH_ * SEQ_;   // 4096
static constexpr int QKVN    = 3 * DMODEL;      // 3072

__device__ inline unsigned short f2bf(float f) {
  union { float f; unsigned int u; } x; x.f = f;
  unsigned int r = (x.u + 0x7FFFu + ((x.u >> 16) & 1u)) >> 16;
  return (unsigned short)r;
}
__device__ inline float bf2f(unsigned short b) {
  union { unsigned int u; float f; } x; x.u = ((unsigned int)b) << 16;
  return x.f;
}

__device__ inline void gload_lds16(const void* g, void* l) {
  __builtin_amdgcn_global_load_lds(
      (const __attribute__((address_space(1))) void*)g,
      (__attribute__((address_space(3))) void*)l, 16, 0, 0);
}

// ---- shared MFMA GEMM core: 128x64 tile, K=1024, BK=32, 4 waves (2x2) ----
// aSrc0/aSrc1: per-lane global ptrs for this wave's two 16-row A chunks
// (already include (lane>>2)*1024 + (lane&3)*8). bSrc likewise for B chunk.
__device__ __forceinline__ void gemm_core_k1024(
    const unsigned short* __restrict__ aSrc0, const unsigned short* __restrict__ aSrc1,
    const unsigned short* __restrict__ bSrc,
    unsigned short* Al, unsigned short* Bl,
    const int wave, const int lane, floatx4 (&acc)[4][2]) {
  const int quad = lane >> 4, l16 = lane & 15;
  const int wm = (wave >> 1) * 64, wn = (wave & 1) * 32;
  unsigned short* AlD0 = Al + (wave * 32) * 32;
  unsigned short* AlD1 = Al + (wave * 32 + 16) * 32;
  unsigned short* BlD  = Bl + (wave * 16) * 32;
  for (int k0 = 0; k0 < 1024; k0 += 32) {
    __syncthreads();
    gload_lds16(aSrc0 + k0, AlD0);
    gload_lds16(aSrc1 + k0, AlD1);
    gload_lds16(bSrc  + k0, BlD);
    __syncthreads();
    shortx8 af[4], bfr[2];
    #pragma unroll
    for (int s = 0; s < 4; s++)
      af[s] = *(const shortx8*)&Al[(wm + s * 16 + l16) * 32 + quad * 8];
    #pragma unroll
    for (int s = 0; s < 2; s++)
      bfr[s] = *(const shortx8*)&Bl[(wn + s * 16 + l16) * 32 + quad * 8];
    #pragma unroll
    for (int sm = 0; sm < 4; sm++)
      #pragma unroll
      for (int sn = 0; sn < 2; sn++)
        acc[sm][sn] = __builtin_amdgcn_mfma_f32_16x16x32_bf16(af[sm], bfr[sn], acc[sm][sn], 0, 0, 0);
  }
}

// =================== K1: LN + weight converts + mask/tier lists ===================
// blocks [0,3072): cvtT w_qkv -> wqT[n][k]
// [3072,7168): LayerNorm rows
// [7168,8192): cvtT w_out -> woT[n][k]
// [8192,9216): Wvs[k][v] = bf16(w_qkv[k][2048+v])
// [9216,11264): mask row i: top-tier col list + tmx + qlist fixed slots
__global__ __launch_bounds__(256) void k1_prep(
    const float* __restrict__ x, const float* __restrict__ w_qkv,
    const float* __restrict__ w_out, const float* __restrict__ gamma,
    const float* __restrict__ beta, const int* __restrict__ ridx,
    unsigned short* __restrict__ xn, unsigned short* __restrict__ wqT,
    unsigned short* __restrict__ woT, unsigned short* __restrict__ Wvs,
    int* __restrict__ cols, int* __restrict__ cnt, int* __restrict__ tmx,
    int* __restrict__ qlist) {
  __shared__ float tile[32][33];
  __shared__ float red[4], red2[4];
  __shared__ int rl[RTOK];
  __shared__ int scount, stm;
  const int bx = blockIdx.x;
  const int t = threadIdx.x;
  if (bx < 3072) {
    int n0 = (bx % 96) * 32, k0 = (bx / 96) * 32;
    int tx = t & 31, ty = t >> 5;
    #pragma unroll
    for (int r = ty; r < 32; r += 8)
      tile[r][tx] = w_qkv[(size_t)(k0 + r) * QKVN + n0 + tx];
    __syncthreads();
    #pragma unroll
    for (int r = ty; r < 32; r += 8)
      wqT[(size_t)(n0 + r) * DMODEL + k0 + tx] = f2bf(tile[tx][r]);
  } else if (bx < 7168) {
    int row = bx - 3072;
    const float4* xr = (const float4*)(x + (size_t)row * DMODEL);
    float4 v = xr[t];
    float s = v.x + v.y + v.z + v.w;
    #pragma unroll
    for (int o = 32; o > 0; o >>= 1) s += __shfl_xor(s, o);
    int wave = t >> 6, lane = t & 63;
    if (lane == 0) red[wave] = s;
    __syncthreads();
    float mean = (red[0] + red[1] + red[2] + red[3]) * (1.0f / DMODEL);
    float dx = v.x - mean, dy = v.y - mean, dz = v.z - mean, dw = v.w - mean;
    float q = dx*dx + dy*dy + dz*dz + dw*dw;
    #pragma unroll
    for (int o = 32; o > 0; o >>= 1) q += __shfl_xor(q, o);
    if (lane == 0) red2[wave] = q;
    __syncthreads();
    float var = (red2[0] + red2[1] + red2[2] + red2[3]) * (1.0f / DMODEL);
    float rs = rsqrtf(var + 1e-5f);
    float4 g = ((const float4*)gamma)[t];
    float4 bb = ((const float4*)beta)[t];
    ushort4 outv;
    outv.x = f2bf(dx * rs * g.x + bb.x);
    outv.y = f2bf(dy * rs * g.y + bb.y);
    outv.z = f2bf(dz * rs * g.z + bb.z);
    outv.w = f2bf(dw * rs * g.w + bb.w);
    ((ushort4*)(xn + (size_t)row * DMODEL))[t] = outv;
  } else if (bx < 8192) {
    int idx = bx - 7168;
    int n0 = (idx & 31) * 32, k0 = (idx >> 5) * 32;
    int tx = t & 31, ty = t >> 5;
    #pragma unroll
    for (int r = ty; r < 32; r += 8)
      tile[r][tx] = w_out[(size_t)(k0 + r) * DMODEL + n0 + tx];
    __syncthreads();
    #pragma unroll
    for (int r = ty; r < 32; r += 8)
      woT[(size_t)(n0 + r) * DMODEL + k0 + tx] = f2bf(tile[tx][r]);
  } else if (bx < 9216) {
    int idx = bx - 8192;
    int v0 = (idx & 31) * 32, k0 = (idx >> 5) * 32;
    int tx = t & 31, ty = t >> 5;
    #pragma unroll
    for (int r = ty; r < 32; r += 8)
      Wvs[(size_t)(k0 + r) * DMODEL + v0 + tx] =
          f2bf(w_qkv[(size_t)(k0 + r) * QKVN + 2 * DMODEL + v0 + tx]);
  } else {
    const int i = bx - 9216;
    if (t < RTOK) rl[t] = ridx[i * RTOK + t];
    if (t == 0) { scount = 0; stm = 0; }
    __syncthreads();
    const int wstart = (i - WINDOW_ > 0) ? (i - WINDOW_) : 0;
    const int c = t;
    int j = -1;
    bool valid = false;
    if (c < 65) {                       // window candidates (incl diagonal)
      j = i - WINDOW_ + c;
      valid = (j >= 0);
    } else if (c < 73) {                // global cols outside window
      int g = c - 65;
      j = (g < 4) ? g : (SEQ_ - 8 + g);
      valid = (j <= i) && (j < wstart);
    } else if (c < 73 + RTOK) {         // random cols outside window/global, deduped
      int r = c - 73;
      j = rl[r];
      bool dup = false;
      for (int r2 = 0; r2 < r; r2++) dup = dup || (rl[r2] == j);
      valid = (j <= i) && (j < wstart) && !(j < GTOK || j >= SEQ_ - GTOK) && !dup;
    }
    int tier = -1;
    if (valid) {
      int loc = ((i - j) <= WINDOW_) ? 1 : 0;
      int glb = (j < GTOK || j >= SEQ_ - GTOK) ? 1 : 0;
      int rnd = 0;
      for (int r = 0; r < RTOK; r++) rnd |= (rl[r] == j) ? 1 : 0;
      tier = loc + glb + rnd;
      atomicMax(&stm, tier);
    }
    __syncthreads();
    const int tm = stm;
    if (valid && tier == tm) {
      int pos = atomicAdd(&scount, 1);
      cols[i * 128 + pos] = j;
    }
    __syncthreads();
    if (t == 0) {
      cnt[i] = scount;
      tmx[i] = tm;
      if (i < 68 || i >= SEQ_ - 4) {   // tier-3 candidate rows get fixed qlist slots
        int cc = (i < 68) ? i : 68 + (i - (SEQ_ - 4));
        qlist[cc * 2 + 0] = (tm == 3) ? i : -1;
        qlist[cc * 2 + 1] = (tm == 3) ? (SEQ_ + i) : -1;
      }
    }
  }
}

// =================== K2: Wvo weight-GEMM + tier-3 q/k/v gather-GEMMs ===============
// blocks [0,128): WvoT[n][k] = sum_v woT[n][v]*Wvs[k][v]
// [128,192): gather jobs: 0/1 -> qf slabs (qlist), 2 -> kf (Wk), 3 -> vf (Wv)
__global__ __launch_bounds__(256) void k2_wgemm(
    const unsigned short* __restrict__ woT, const unsigned short* __restrict__ Wvs,
    unsigned short* __restrict__ WvoT, const unsigned short* __restrict__ xn,
    const unsigned short* __restrict__ wqT, const int* __restrict__ qlist,
    unsigned short* __restrict__ qf, unsigned short* __restrict__ kf,
    unsigned short* __restrict__ vf) {
  __shared__ unsigned short Al[128 * 32];
  __shared__ unsigned short Bl[64 * 32];
  const int bx = blockIdx.x, t = threadIdx.x;
  const int wave = t >> 6, lane = t & 63;
  const int lrow = lane >> 2, lkoff = (lane & 3) * 8;
  const int quad = lane >> 4, l16 = lane & 15;
  const int wm = (wave >> 1) * 64, wn = (wave & 1) * 32;
  floatx4 acc[4][2] = {};
  if (bx < 128) {
    const int bm = (bx >> 4) * 128, bn = (bx & 15) * 64;
    const unsigned short* a0 = woT + (size_t)(bm + wave * 32 + lrow) * DMODEL + lkoff;
    const unsigned short* a1 = a0 + 16 * DMODEL;
    const unsigned short* b0 = Wvs + (size_t)(bn + wave * 16 + lrow) * DMODEL + lkoff;
    gemm_core_k1024(a0, a1, b0, Al, Bl, wave, lane, acc);
    #pragma unroll
    for (int sm = 0; sm < 4; sm++)
      #pragma unroll
      for (int sn = 0; sn < 2; sn++)
        #pragma unroll
        for (int r = 0; r < 4; r++) {
          int row = bm + wm + sm * 16 + quad * 4 + r;
          int col = bn + wn + sn * 16 + l16;
          WvoT[(size_t)row * DMODEL + col] = f2bf(acc[sm][sn][r]);
        }
  } else {
    const int idx = bx - 128;
    const int job = idx >> 4, bn = (idx & 15) * 64;
    const int wsel = (job < 2) ? 0 : ((job == 2) ? 1 : 2);
    const unsigned short* BT = wqT + (size_t)wsel * DMODEL * DMODEL;
    unsigned short* dstbuf = (job == 0) ? qf
                           : (job == 1) ? (qf + (size_t)128 * DMODEL)
                           : (job == 2) ? kf : vf;
    int rsrc[2];
    #pragma unroll
    for (int q = 0; q < 2; q++) {
      int m = wave * 32 + q * 16 + lrow;
      int row;
      if (job < 2) {
        int s = job * 128 + m;
        int ql = (s < 144) ? qlist[s] : -1;
        row = (ql < 0) ? 0 : ql;
      } else {
        row = (m < 16) ? ((m >> 3) * SEQ_ + (((m & 7) < 4) ? (m & 7) : (SEQ_ - 8 + (m & 7)))) : 0;
      }
      rsrc[q] = row;
    }
    const unsigned short* a0 = xn + (size_t)rsrc[0] * DMODEL + lkoff;
    const unsigned short* a1 = xn + (size_t)rsrc[1] * DMODEL + lkoff;
    const unsigned short* b0 = BT + (size_t)(bn + wave * 16 + lrow) * DMODEL + lkoff;
    gemm_core_k1024(a0, a1, b0, Al, Bl, wave, lane, acc);
    #pragma unroll
    for (int sm = 0; sm < 4; sm++)
      #pragma unroll
      for (int sn = 0; sn < 2; sn++)
        #pragma unroll
        for (int r = 0; r < 4; r++) {
          int m = wm + sm * 16 + quad * 4 + r;
          int col = bn + wn + sn * 16 + l16;
          dstbuf[(size_t)m * DMODEL + col] = f2bf(acc[sm][sn][r]);
        }
  }
}

// =================== K3: window-tiled xbar + tier-3 softmax ===================
// blocks [0,1024): xbar tile = (batch, 16-row i-tile, 256-dim tile); window rows in LDS
// [1024,1060): tier-3 attn fix: wave per qlist slot -> vbar row
__global__ __launch_bounds__(256) void k3_xbar(
    const unsigned short* __restrict__ xn, const int* __restrict__ cols,
    const int* __restrict__ cnt, const int* __restrict__ tmx,
    const int* __restrict__ qlist, const unsigned short* __restrict__ qf,
    const unsigned short* __restrict__ kf, const unsigned short* __restrict__ vf,
    unsigned short* __restrict__ xbar, unsigned short* __restrict__ vbar) {
  const int bx = blockIdx.x, t = threadIdx.x;
  const int wave = t >> 6, lane = t & 63;
  if (bx < 1024) {
    __shared__ unsigned short win[80][256];   // rows [i0-64, i0+15] x 256 dims
    const int b = bx >> 9, rest = bx & 511;
    const int i0 = (rest >> 2) * 16, dimbase = (rest & 3) * 256;
    const size_t xnb = (size_t)(b * SEQ_) * DMODEL;
    // stage 80 window rows (512 B each), 4 rows per iteration
    #pragma unroll 4
    for (int it = 0; it < 20; it++) {
      int r = it * 4 + wave;
      int gr = i0 - 64 + r;
      if (gr >= 0)
        *(ushort4*)&win[r][lane * 4] =
            *(const ushort4*)(xn + xnb + (size_t)gr * DMODEL + dimbase + lane * 4);
    }
    __syncthreads();
    // wave w handles rows i0+w*4 .. i0+w*4+3
    for (int rr = 0; rr < 4; rr++) {
      const int i = i0 + wave * 4 + rr;
      const int tm = tmx[i], n = cnt[i];
      ushort4 o;
      if (tm == 3) {
        o.x = o.y = o.z = o.w = 0;
      } else {
        float sx = 0.f, sy = 0.f, sz = 0.f, sw = 0.f;
        const int lo = i0 - 64;
        for (int c = 0; c < n; c++) {
          int j = cols[i * 128 + c];
          ushort4 v;
          if (j >= lo)
            v = *(const ushort4*)&win[j - lo][lane * 4];
          else
            v = *(const ushort4*)(xn + xnb + (size_t)j * DMODEL + dimbase + lane * 4);
          sx += bf2f(v.x); sy += bf2f(v.y); sz += bf2f(v.z); sw += bf2f(v.w);
        }
        float inv = 1.0f / (float)n;
        o.x = f2bf(sx * inv); o.y = f2bf(sy * inv);
        o.z = f2bf(sz * inv); o.w = f2bf(sw * inv);
      }
      *(ushort4*)(xbar + (size_t)(b * SEQ_ + i) * DMODEL + dimbase + lane * 4) = o;
    }
  } else {
    const int s = (bx - 1024) * 4 + wave;       // slot in [0,144)
    const int dst = (s < 144) ? qlist[s] : -1;
    if (dst < 0) return;
    const int b = dst >> 11, i = dst & (SEQ_ - 1);
    const int n = cnt[i];
    int myk = 0;
    if (lane < n) {
      int kj = cols[i * 128 + lane];
      myk = b * 8 + ((kj < 4) ? kj : (kj - (SEQ_ - 8)));
    }
    for (int h = 0; h < NHEADS; h++) {
      float qd = bf2f(qf[(size_t)s * DMODEL + h * HDIM + lane]);
      float w[8];
      float m = -1e30f;
      for (int c = 0; c < n; c++) {
        int ks = __shfl(myk, c);
        float kd = bf2f(kf[(size_t)ks * DMODEL + h * HDIM + lane]);
        float p = qd * kd;
        #pragma unroll
        for (int o = 32; o > 0; o >>= 1) p += __shfl_xor(p, o);
        p *= 0.375f;                    // 3 * (q.k / 8)
        w[c] = p;
        m = fmaxf(m, p);
      }
      float denom = 0.f, acc = 0.f;
      for (int c = 0; c < n; c++) {
        int ks = __shfl(myk, c);
        float e = __expf(w[c] - m);
        denom += e;
        acc += e * bf2f(vf[(size_t)ks * DMODEL + h * HDIM + lane]);
      }
      vbar[(size_t)s * DMODEL + h * HDIM + lane] = f2bf(acc / denom);
    }
  }
}

// =================== K4: main fused GEMM + tier-3 row fixup GEMM ===================
// blocks [0,512): out[m] = xbar[m] @ WvoT^T + x[m]   (skip rows with tmx==3)
// [512,544): out[qlist[m]] = vbar[m] @ woT^T + x[qlist[m]]
__global__ __launch_bounds__(256) void k4_final(
    const unsigned short* __restrict__ xbar, const unsigned short* __restrict__ WvoT,
    const unsigned short* __restrict__ vbar, const unsigned short* __restrict__ woT,
    const int* __restrict__ qlist, const int* __restrict__ tmx,
    const float* __restrict__ x, float* __restrict__ out) {
  __shared__ unsigned short Al[128 * 32];
  __shared__ unsigned short Bl[64 * 32];
  __shared__ int rowinf[128];
  const int bx = blockIdx.x, t = threadIdx.x;
  const int wave = t >> 6, lane = t & 63;
  const int lrow = lane >> 2, lkoff = (lane & 3) * 8;
  const int quad = lane >> 4, l16 = lane & 15;
  const int wm = (wave >> 1) * 64, wn = (wave & 1) * 32;
  floatx4 acc[4][2] = {};
  if (bx < 512) {
    const int bm = (bx >> 4) * 128, bn = (bx & 15) * 64;
    if (t < 128) rowinf[t] = tmx[(bm + t) & (SEQ_ - 1)];
    const unsigned short* a0 = xbar + (size_t)(bm + wave * 32 + lrow) * DMODEL + lkoff;
    const unsigned short* a1 = a0 + 16 * DMODEL;
    const unsigned short* b0 = WvoT + (size_t)(bn + wave * 16 + lrow) * DMODEL + lkoff;
    gemm_core_k1024(a0, a1, b0, Al, Bl, wave, lane, acc);  // first barrier publishes rowinf
    #pragma unroll
    for (int sm = 0; sm < 4; sm++)
      #pragma unroll
      for (int sn = 0; sn < 2; sn++)
        #pragma unroll
        for (int r = 0; r < 4; r++) {
          int m = wm + sm * 16 + quad * 4 + r;
          if (rowinf[m] != 3) {
            int col = bn + wn + sn * 16 + l16;
            size_t off = (size_t)(bm + m) * DMODEL + col;
            out[off] = acc[sm][sn][r] + x[off];
          }
        }
  } else {
    const int idx = bx - 512;
    const int bm = (idx >> 4) * 128, bn = (idx & 15) * 64;
    if (t < 128) {
      int s = bm + t;
      rowinf[t] = (s < 144) ? qlist[s] : -1;
    }
    const unsigned short* a0 = vbar + (size_t)(bm + wave * 32 + lrow) * DMODEL + lkoff;
    const unsigned short* a1 = a0 + 16 * DMODEL;
    const unsigned short* b0 = woT + (size_t)(bn + wave * 16 + lrow) * DMODEL + lkoff;
    gemm_core_k1024(a0, a1, b0, Al, Bl, wave, lane, acc);
    #pragma unroll
    for (int sm = 0; sm < 4; sm++)
      #pragma unroll
      for (int sn = 0; sn < 2; sn++)
        #pragma unroll
        for (int r = 0; r < 4; r++) {
          int m = wm + sm * 16 + quad * 4 + r;
          int dst = rowinf[m];
          if (dst >= 0) {
            int col = bn + wn + sn * 16 + l16;
            size_t off = (size_t)dst * DMODEL + col;
            out[off] = acc[sm][sn][r] + x[off];
          }
        }
  }
}

extern "C" void kernel_launch(void* const* d_in, const int* in_sizes, int n_in,
                              void* d_out, int out_size, void* d_ws, size_t ws_size,
                              hipStream_t stream) {
  const float* x     = (const float*)d_in[0];
  const float* w_qkv = (const float*)d_in[1];
  const float* w_out = (const float*)d_in[2];
  const float* gamma = (const float*)d_in[3];
  const float* beta  = (const float*)d_in[4];
  const int*   ridx  = (const int*)d_in[5];
  float* out = (float*)d_out;

  char* ws = (char*)d_ws;
  size_t off = 0;
  auto alloc = [&](size_t bytes) {
    char* p = ws + off;
    off = (off + bytes + 255) & ~(size_t)255;
    return p;
  };
  unsigned short* xn   = (unsigned short*)alloc((size_t)ROWS * DMODEL * 2);     // 8 MB
  unsigned short* wqT  = (unsigned short*)alloc((size_t)QKVN * DMODEL * 2);     // 6 MB
  unsigned short* woT  = (unsigned short*)alloc((size_t)DMODEL * DMODEL * 2);   // 2 MB
  unsigned short* Wvs  = (unsigned short*)alloc((size_t)DMODEL * DMODEL * 2);   // 2 MB
  unsigned short* WvoT = (unsigned short*)alloc((size_t)DMODEL * DMODEL * 2);   // 2 MB
  unsigned short* xbar = (unsigned short*)alloc((size_t)ROWS * DMODEL * 2);     // 8 MB
  unsigned short* qf   = (unsigned short*)alloc((size_t)256 * DMODEL * 2);
  unsigned short* kf   = (unsigned short*)alloc((size_t)128 * DMODEL * 2);
  unsigned short* vf   = (unsigned short*)alloc((size_t)128 * DMODEL * 2);
  unsigned short* vbar = (unsigned short*)alloc((size_t)256 * DMODEL * 2);
  int* cols  = (int*)alloc((size_t)SEQ_ * 128 * 4);                             // 1 MB
  int* cnt   = (int*)alloc((size_t)SEQ_ * 4);
  int* tmx   = (int*)alloc((size_t)SEQ_ * 4);
  int* qlist = (int*)alloc(256 * 4);

  hipLaunchKernelGGL(k1_prep, dim3(11264), dim3(256), 0, stream,
                     x, w_qkv, w_out, gamma, beta, ridx,
                     xn, wqT, woT, Wvs, cols, cnt, tmx, qlist);
  hipLaunchKernelGGL(k2_wgemm, dim3(192), dim3(256), 0, stream,
                     woT, Wvs, WvoT, xn, wqT, qlist, qf, kf, vf);
  hipLaunchKernelGGL(k3_xbar, dim3(1060), dim3(256), 0, stream,
                     xn, cols, cnt, tmx, qlist, qf, kf, vf, xbar, vbar);
  hipLaunchKernelGGL(k4_final, dim3(544), dim3(256), 0, stream,
                     xbar, WvoT, vbar, woT, qlist, tmx, x, out);
}

// Round 7
// 186.666 us; speedup vs baseline: 1.2540x; 1.1275x over previous
//
#include <hip/hip_runtime.h>
#include <stdint.h>

typedef __attribute__((ext_vector_type(8))) short shortx8;
typedef __attribute__((ext_vector_type(4))) float floatx4;

static constexpr int SEQ_    = 2048;
static constexpr int DMODEL  = 1024;
static constexpr int HDIM    = 64;
static constexpr int BATCH_  = 2;
static constexpr int NHEADS  = 16;
static constexpr int WINDOW_ = 64;
static constexpr int GTOK    = 4;
static constexpr int RTOK    = 32;
static constexpr int ROWS    = BATCH_ * SEQ_;   // 4096
static constexpr int QKVN    = 3 * DMODEL;      // 3072

__device__ inline unsigned short f2bf(float f) {
  union { float f; unsigned int u; } x; x.f = f;
  unsigned int r = (x.u + 0x7FFFu + ((x.u >> 16) & 1u)) >> 16;
  return (unsigned short)r;
}
__device__ inline float bf2f(unsigned short b) {
  union { unsigned int u; float f; } x; x.u = ((unsigned int)b) << 16;
  return x.f;
}

__device__ inline void gload_lds16(const void* g, void* l) {
  __builtin_amdgcn_global_load_lds(
      (const __attribute__((address_space(1))) void*)g,
      (__attribute__((address_space(3))) void*)l, 16, 0, 0);
}

// ---- shared MFMA GEMM core: 128x64 tile, K=1024, BK=32, 4 waves (2x2) ----
__device__ __forceinline__ void gemm_core_k1024(
    const unsigned short* __restrict__ aSrc0, const unsigned short* __restrict__ aSrc1,
    const unsigned short* __restrict__ bSrc,
    unsigned short* Al, unsigned short* Bl,
    const int wave, const int lane, floatx4 (&acc)[4][2]) {
  const int quad = lane >> 4, l16 = lane & 15;
  const int wm = (wave >> 1) * 64, wn = (wave & 1) * 32;
  unsigned short* AlD0 = Al + (wave * 32) * 32;
  unsigned short* AlD1 = Al + (wave * 32 + 16) * 32;
  unsigned short* BlD  = Bl + (wave * 16) * 32;
  for (int k0 = 0; k0 < 1024; k0 += 32) {
    __syncthreads();
    gload_lds16(aSrc0 + k0, AlD0);
    gload_lds16(aSrc1 + k0, AlD1);
    gload_lds16(bSrc  + k0, BlD);
    __syncthreads();
    shortx8 af[4], bfr[2];
    #pragma unroll
    for (int s = 0; s < 4; s++)
      af[s] = *(const shortx8*)&Al[(wm + s * 16 + l16) * 32 + quad * 8];
    #pragma unroll
    for (int s = 0; s < 2; s++)
      bfr[s] = *(const shortx8*)&Bl[(wn + s * 16 + l16) * 32 + quad * 8];
    #pragma unroll
    for (int sm = 0; sm < 4; sm++)
      #pragma unroll
      for (int sn = 0; sn < 2; sn++)
        acc[sm][sn] = __builtin_amdgcn_mfma_f32_16x16x32_bf16(af[sm], bfr[sn], acc[sm][sn], 0, 0, 0);
  }
}

// =================== K1: LN + weight converts + mask/tier lists ===================
__global__ __launch_bounds__(256) void k1_prep(
    const float* __restrict__ x, const float* __restrict__ w_qkv,
    const float* __restrict__ w_out, const float* __restrict__ gamma,
    const float* __restrict__ beta, const int* __restrict__ ridx,
    unsigned short* __restrict__ xn, unsigned short* __restrict__ wqT,
    unsigned short* __restrict__ woT, unsigned short* __restrict__ Wvs,
    int* __restrict__ cols, int* __restrict__ cnt, int* __restrict__ tmx,
    int* __restrict__ qlist) {
  __shared__ float tile[32][33];
  __shared__ float red[4], red2[4];
  __shared__ int rl[RTOK];
  __shared__ int scount, stm;
  const int bx = blockIdx.x;
  const int t = threadIdx.x;
  if (bx < 3072) {
    int n0 = (bx % 96) * 32, k0 = (bx / 96) * 32;
    int tx = t & 31, ty = t >> 5;
    #pragma unroll
    for (int r = ty; r < 32; r += 8)
      tile[r][tx] = w_qkv[(size_t)(k0 + r) * QKVN + n0 + tx];
    __syncthreads();
    #pragma unroll
    for (int r = ty; r < 32; r += 8)
      wqT[(size_t)(n0 + r) * DMODEL + k0 + tx] = f2bf(tile[tx][r]);
  } else if (bx < 7168) {
    int row = bx - 3072;
    const float4* xr = (const float4*)(x + (size_t)row * DMODEL);
    float4 v = xr[t];
    float s = v.x + v.y + v.z + v.w;
    #pragma unroll
    for (int o = 32; o > 0; o >>= 1) s += __shfl_xor(s, o);
    int wave = t >> 6, lane = t & 63;
    if (lane == 0) red[wave] = s;
    __syncthreads();
    float mean = (red[0] + red[1] + red[2] + red[3]) * (1.0f / DMODEL);
    float dx = v.x - mean, dy = v.y - mean, dz = v.z - mean, dw = v.w - mean;
    float q = dx*dx + dy*dy + dz*dz + dw*dw;
    #pragma unroll
    for (int o = 32; o > 0; o >>= 1) q += __shfl_xor(q, o);
    if (lane == 0) red2[wave] = q;
    __syncthreads();
    float var = (red2[0] + red2[1] + red2[2] + red2[3]) * (1.0f / DMODEL);
    float rs = rsqrtf(var + 1e-5f);
    float4 g = ((const float4*)gamma)[t];
    float4 bb = ((const float4*)beta)[t];
    ushort4 outv;
    outv.x = f2bf(dx * rs * g.x + bb.x);
    outv.y = f2bf(dy * rs * g.y + bb.y);
    outv.z = f2bf(dz * rs * g.z + bb.z);
    outv.w = f2bf(dw * rs * g.w + bb.w);
    ((ushort4*)(xn + (size_t)row * DMODEL))[t] = outv;
  } else if (bx < 8192) {
    int idx = bx - 7168;
    int n0 = (idx & 31) * 32, k0 = (idx >> 5) * 32;
    int tx = t & 31, ty = t >> 5;
    #pragma unroll
    for (int r = ty; r < 32; r += 8)
      tile[r][tx] = w_out[(size_t)(k0 + r) * DMODEL + n0 + tx];
    __syncthreads();
    #pragma unroll
    for (int r = ty; r < 32; r += 8)
      woT[(size_t)(n0 + r) * DMODEL + k0 + tx] = f2bf(tile[tx][r]);
  } else if (bx < 9216) {
    int idx = bx - 8192;
    int v0 = (idx & 31) * 32, k0 = (idx >> 5) * 32;
    int tx = t & 31, ty = t >> 5;
    #pragma unroll
    for (int r = ty; r < 32; r += 8)
      Wvs[(size_t)(k0 + r) * DMODEL + v0 + tx] =
          f2bf(w_qkv[(size_t)(k0 + r) * QKVN + 2 * DMODEL + v0 + tx]);
  } else {
    const int i = bx - 9216;
    if (t < RTOK) rl[t] = ridx[i * RTOK + t];
    if (t == 0) { scount = 0; stm = 0; }
    __syncthreads();
    const int wstart = (i - WINDOW_ > 0) ? (i - WINDOW_) : 0;
    const int c = t;
    int j = -1;
    bool valid = false;
    if (c < 65) {                       // window candidates (incl diagonal)
      j = i - WINDOW_ + c;
      valid = (j >= 0);
    } else if (c < 73) {                // global cols outside window
      int g = c - 65;
      j = (g < 4) ? g : (SEQ_ - 8 + g);
      valid = (j <= i) && (j < wstart);
    } else if (c < 73 + RTOK) {         // random cols outside window/global, deduped
      int r = c - 73;
      j = rl[r];
      bool dup = false;
      for (int r2 = 0; r2 < r; r2++) dup = dup || (rl[r2] == j);
      valid = (j <= i) && (j < wstart) && !(j < GTOK || j >= SEQ_ - GTOK) && !dup;
    }
    int tier = -1;
    if (valid) {
      int loc = ((i - j) <= WINDOW_) ? 1 : 0;
      int glb = (j < GTOK || j >= SEQ_ - GTOK) ? 1 : 0;
      int rnd = 0;
      for (int r = 0; r < RTOK; r++) rnd |= (rl[r] == j) ? 1 : 0;
      tier = loc + glb + rnd;
      atomicMax(&stm, tier);
    }
    __syncthreads();
    const int tm = stm;
    if (valid && tier == tm) {
      int pos = atomicAdd(&scount, 1);
      cols[i * 128 + pos] = j;
    }
    __syncthreads();
    if (t == 0) {
      cnt[i] = scount;
      tmx[i] = tm;
      if (i < 68 || i >= SEQ_ - 4) {   // tier-3 candidate rows get fixed qlist slots
        int cc = (i < 68) ? i : 68 + (i - (SEQ_ - 4));
        qlist[cc * 2 + 0] = (tm == 3) ? i : -1;
        qlist[cc * 2 + 1] = (tm == 3) ? (SEQ_ + i) : -1;
      }
    }
  }
}

// =================== K2: Wvo weight-GEMM + tier-3 q/k/v gather-GEMMs ===============
__global__ __launch_bounds__(256) void k2_wgemm(
    const unsigned short* __restrict__ woT, const unsigned short* __restrict__ Wvs,
    unsigned short* __restrict__ WvoT, const unsigned short* __restrict__ xn,
    const unsigned short* __restrict__ wqT, const int* __restrict__ qlist,
    unsigned short* __restrict__ qf, unsigned short* __restrict__ kf,
    unsigned short* __restrict__ vf) {
  __shared__ unsigned short Al[128 * 32];
  __shared__ unsigned short Bl[64 * 32];
  const int bx = blockIdx.x, t = threadIdx.x;
  const int wave = t >> 6, lane = t & 63;
  const int lrow = lane >> 2, lkoff = (lane & 3) * 8;
  const int quad = lane >> 4, l16 = lane & 15;
  const int wm = (wave >> 1) * 64, wn = (wave & 1) * 32;
  floatx4 acc[4][2] = {};
  if (bx < 128) {
    const int bm = (bx >> 4) * 128, bn = (bx & 15) * 64;
    const unsigned short* a0 = woT + (size_t)(bm + wave * 32 + lrow) * DMODEL + lkoff;
    const unsigned short* a1 = a0 + 16 * DMODEL;
    const unsigned short* b0 = Wvs + (size_t)(bn + wave * 16 + lrow) * DMODEL + lkoff;
    gemm_core_k1024(a0, a1, b0, Al, Bl, wave, lane, acc);
    #pragma unroll
    for (int sm = 0; sm < 4; sm++)
      #pragma unroll
      for (int sn = 0; sn < 2; sn++)
        #pragma unroll
        for (int r = 0; r < 4; r++) {
          int row = bm + wm + sm * 16 + quad * 4 + r;
          int col = bn + wn + sn * 16 + l16;
          WvoT[(size_t)row * DMODEL + col] = f2bf(acc[sm][sn][r]);
        }
  } else {
    const int idx = bx - 128;
    const int job = idx >> 4, bn = (idx & 15) * 64;
    const int wsel = (job < 2) ? 0 : ((job == 2) ? 1 : 2);
    const unsigned short* BT = wqT + (size_t)wsel * DMODEL * DMODEL;
    unsigned short* dstbuf = (job == 0) ? qf
                           : (job == 1) ? (qf + (size_t)128 * DMODEL)
                           : (job == 2) ? kf : vf;
    int rsrc[2];
    #pragma unroll
    for (int q = 0; q < 2; q++) {
      int m = wave * 32 + q * 16 + lrow;
      int row;
      if (job < 2) {
        int s = job * 128 + m;
        int ql = (s < 144) ? qlist[s] : -1;
        row = (ql < 0) ? 0 : ql;
      } else {
        row = (m < 16) ? ((m >> 3) * SEQ_ + (((m & 7) < 4) ? (m & 7) : (SEQ_ - 8 + (m & 7)))) : 0;
      }
      rsrc[q] = row;
    }
    const unsigned short* a0 = xn + (size_t)rsrc[0] * DMODEL + lkoff;
    const unsigned short* a1 = xn + (size_t)rsrc[1] * DMODEL + lkoff;
    const unsigned short* b0 = BT + (size_t)(bn + wave * 16 + lrow) * DMODEL + lkoff;
    gemm_core_k1024(a0, a1, b0, Al, Bl, wave, lane, acc);
    #pragma unroll
    for (int sm = 0; sm < 4; sm++)
      #pragma unroll
      for (int sn = 0; sn < 2; sn++)
        #pragma unroll
        for (int r = 0; r < 4; r++) {
          int m = wm + sm * 16 + quad * 4 + r;
          int col = bn + wn + sn * 16 + l16;
          dstbuf[(size_t)m * DMODEL + col] = f2bf(acc[sm][sn][r]);
        }
  }
}

// =================== K3: window-tiled xbar + tier-3 softmax ===================
// blocks [0,1024): xbar tile = (batch, 16-row i-tile, 256-dim tile); window rows in LDS.
// col indices live in 2 regs/lane, broadcast via __shfl (v_readlane) -> no memory in
// the dependent chain; unroll x4 with independent accumulators.
// [1024,1060): tier-3 attn fix: wave per qlist slot -> vbar row
__global__ __launch_bounds__(256) void k3_xbar(
    const unsigned short* __restrict__ xn, const int* __restrict__ cols,
    const int* __restrict__ cnt, const int* __restrict__ tmx,
    const int* __restrict__ qlist, const unsigned short* __restrict__ qf,
    const unsigned short* __restrict__ kf, const unsigned short* __restrict__ vf,
    unsigned short* __restrict__ xbar, unsigned short* __restrict__ vbar) {
  const int bx = blockIdx.x, t = threadIdx.x;
  const int wave = t >> 6, lane = t & 63;
  if (bx < 1024) {
    __shared__ unsigned short win[80][256];   // rows [i0-64, i0+15] x 256 dims
    const int b = bx >> 9, rest = bx & 511;
    const int i0 = (rest >> 2) * 16, dimbase = (rest & 3) * 256;
    const size_t xnb = (size_t)(b * SEQ_) * DMODEL;
    const int lo = i0 - 64;
    // stage 80 window rows (512 B each), 4 rows per iteration
    #pragma unroll 4
    for (int it = 0; it < 20; it++) {
      int r = it * 4 + wave;
      int gr = lo + r;
      if (gr >= 0)
        *(ushort4*)&win[r][lane * 4] =
            *(const ushort4*)(xn + xnb + (size_t)gr * DMODEL + dimbase + lane * 4);
    }
    __syncthreads();
    const unsigned short* xnd = xn + xnb + dimbase + lane * 4;
    // wave w handles rows i0+w*4 .. i0+w*4+3
    for (int rr = 0; rr < 4; rr++) {
      const int i = i0 + wave * 4 + rr;
      const int tm = tmx[i], n = cnt[i];
      ushort4 o;
      if (tm == 3) {
        o.x = o.y = o.z = o.w = 0;
      } else {
        // preload this row's col indices: lane c holds cols[c], cols[64+c]
        int jr0 = cols[i * 128 + lane];
        int jr1 = cols[i * 128 + 64 + lane];
        float4 s0 = {0,0,0,0}, s1 = {0,0,0,0}, s2 = {0,0,0,0}, s3 = {0,0,0,0};
        auto ldcol = [&](int j) -> ushort4 {
          if (j >= lo) return *(const ushort4*)&win[j - lo][lane * 4];
          return *(const ushort4*)(xnd + (size_t)j * DMODEL);
        };
        auto acc4 = [](float4& s, ushort4 v) {
          s.x += bf2f(v.x); s.y += bf2f(v.y); s.z += bf2f(v.z); s.w += bf2f(v.w);
        };
        const int nA = (n < 64) ? n : 64;
        int c = 0;
        for (; c + 4 <= nA; c += 4) {
          int j0 = __shfl(jr0, c), j1 = __shfl(jr0, c + 1);
          int j2 = __shfl(jr0, c + 2), j3 = __shfl(jr0, c + 3);
          ushort4 v0 = ldcol(j0), v1 = ldcol(j1), v2 = ldcol(j2), v3 = ldcol(j3);
          acc4(s0, v0); acc4(s1, v1); acc4(s2, v2); acc4(s3, v3);
        }
        for (; c < nA; c++) acc4(s0, ldcol(__shfl(jr0, c)));
        c = 64;
        for (; c + 4 <= n; c += 4) {
          int j0 = __shfl(jr1, c - 64), j1 = __shfl(jr1, c - 63);
          int j2 = __shfl(jr1, c - 62), j3 = __shfl(jr1, c - 61);
          ushort4 v0 = ldcol(j0), v1 = ldcol(j1), v2 = ldcol(j2), v3 = ldcol(j3);
          acc4(s0, v0); acc4(s1, v1); acc4(s2, v2); acc4(s3, v3);
        }
        for (; c < n; c++) acc4(s0, ldcol(__shfl(jr1, c - 64)));
        float inv = 1.0f / (float)n;
        o.x = f2bf((s0.x + s1.x + s2.x + s3.x) * inv);
        o.y = f2bf((s0.y + s1.y + s2.y + s3.y) * inv);
        o.z = f2bf((s0.z + s1.z + s2.z + s3.z) * inv);
        o.w = f2bf((s0.w + s1.w + s2.w + s3.w) * inv);
      }
      *(ushort4*)(xbar + (size_t)(b * SEQ_ + i) * DMODEL + dimbase + lane * 4) = o;
    }
  } else {
    const int s = (bx - 1024) * 4 + wave;       // slot in [0,144)
    const int dst = (s < 144) ? qlist[s] : -1;
    if (dst < 0) return;
    const int b = dst >> 11, i = dst & (SEQ_ - 1);
    const int n = cnt[i];
    int myk = 0;
    if (lane < n) {
      int kj = cols[i * 128 + lane];
      myk = b * 8 + ((kj < 4) ? kj : (kj - (SEQ_ - 8)));
    }
    for (int h = 0; h < NHEADS; h++) {
      float qd = bf2f(qf[(size_t)s * DMODEL + h * HDIM + lane]);
      float w[8];
      float m = -1e30f;
      for (int c = 0; c < n; c++) {
        int ks = __shfl(myk, c);
        float kd = bf2f(kf[(size_t)ks * DMODEL + h * HDIM + lane]);
        float p = qd * kd;
        #pragma unroll
        for (int o = 32; o > 0; o >>= 1) p += __shfl_xor(p, o);
        p *= 0.375f;                    // 3 * (q.k / 8)
        w[c] = p;
        m = fmaxf(m, p);
      }
      float denom = 0.f, acc = 0.f;
      for (int c = 0; c < n; c++) {
        int ks = __shfl(myk, c);
        float e = __expf(w[c] - m);
        denom += e;
        acc += e * bf2f(vf[(size_t)ks * DMODEL + h * HDIM + lane]);
      }
      vbar[(size_t)s * DMODEL + h * HDIM + lane] = f2bf(acc / denom);
    }
  }
}

// =================== K4: main fused GEMM + tier-3 row fixup GEMM ===================
__global__ __launch_bounds__(256) void k4_final(
    const unsigned short* __restrict__ xbar, const unsigned short* __restrict__ WvoT,
    const unsigned short* __restrict__ vbar, const unsigned short* __restrict__ woT,
    const int* __restrict__ qlist, const int* __restrict__ tmx,
    const float* __restrict__ x, float* __restrict__ out) {
  __shared__ unsigned short Al[128 * 32];
  __shared__ unsigned short Bl[64 * 32];
  __shared__ int rowinf[128];
  const int bx = blockIdx.x, t = threadIdx.x;
  const int wave = t >> 6, lane = t & 63;
  const int lrow = lane >> 2, lkoff = (lane & 3) * 8;
  const int quad = lane >> 4, l16 = lane & 15;
  const int wm = (wave >> 1) * 64, wn = (wave & 1) * 32;
  floatx4 acc[4][2] = {};
  if (bx < 512) {
    const int bm = (bx >> 4) * 128, bn = (bx & 15) * 64;
    if (t < 128) rowinf[t] = tmx[(bm + t) & (SEQ_ - 1)];
    const unsigned short* a0 = xbar + (size_t)(bm + wave * 32 + lrow) * DMODEL + lkoff;
    const unsigned short* a1 = a0 + 16 * DMODEL;
    const unsigned short* b0 = WvoT + (size_t)(bn + wave * 16 + lrow) * DMODEL + lkoff;
    gemm_core_k1024(a0, a1, b0, Al, Bl, wave, lane, acc);  // first barrier publishes rowinf
    #pragma unroll
    for (int sm = 0; sm < 4; sm++)
      #pragma unroll
      for (int sn = 0; sn < 2; sn++)
        #pragma unroll
        for (int r = 0; r < 4; r++) {
          int m = wm + sm * 16 + quad * 4 + r;
          if (rowinf[m] != 3) {
            int col = bn + wn + sn * 16 + l16;
            size_t off = (size_t)(bm + m) * DMODEL + col;
            out[off] = acc[sm][sn][r] + x[off];
          }
        }
  } else {
    const int idx = bx - 512;
    const int bm = (idx >> 4) * 128, bn = (idx & 15) * 64;
    if (t < 128) {
      int s = bm + t;
      rowinf[t] = (s < 144) ? qlist[s] : -1;
    }
    const unsigned short* a0 = vbar + (size_t)(bm + wave * 32 + lrow) * DMODEL + lkoff;
    const unsigned short* a1 = a0 + 16 * DMODEL;
    const unsigned short* b0 = woT + (size_t)(bn + wave * 16 + lrow) * DMODEL + lkoff;
    gemm_core_k1024(a0, a1, b0, Al, Bl, wave, lane, acc);
    #pragma unroll
    for (int sm = 0; sm < 4; sm++)
      #pragma unroll
      for (int sn = 0; sn < 2; sn++)
        #pragma unroll
        for (int r = 0; r < 4; r++) {
          int m = wm + sm * 16 + quad * 4 + r;
          int dst = rowinf[m];
          if (dst >= 0) {
            int col = bn + wn + sn * 16 + l16;
            size_t off = (size_t)dst * DMODEL + col;
            out[off] = acc[sm][sn][r] + x[off];
          }
        }
  }
}

extern "C" void kernel_launch(void* const* d_in, const int* in_sizes, int n_in,
                              void* d_out, int out_size, void* d_ws, size_t ws_size,
                              hipStream_t stream) {
  const float* x     = (const float*)d_in[0];
  const float* w_qkv = (const float*)d_in[1];
  const float* w_out = (const float*)d_in[2];
  const float* gamma = (const float*)d_in[3];
  const float* beta  = (const float*)d_in[4];
  const int*   ridx  = (const int*)d_in[5];
  float* out = (float*)d_out;

  char* ws = (char*)d_ws;
  size_t off = 0;
  auto alloc = [&](size_t bytes) {
    char* p = ws + off;
    off = (off + bytes + 255) & ~(size_t)255;
    return p;
  };
  unsigned short* xn   = (unsigned short*)alloc((size_t)ROWS * DMODEL * 2);     // 8 MB
  unsigned short* wqT  = (unsigned short*)alloc((size_t)QKVN * DMODEL * 2);     // 6 MB
  unsigned short* woT  = (unsigned short*)alloc((size_t)DMODEL * DMODEL * 2);   // 2 MB
  unsigned short* Wvs  = (unsigned short*)alloc((size_t)DMODEL * DMODEL * 2);   // 2 MB
  unsigned short* WvoT = (unsigned short*)alloc((size_t)DMODEL * DMODEL * 2);   // 2 MB
  unsigned short* xbar = (unsigned short*)alloc((size_t)ROWS * DMODEL * 2);     // 8 MB
  unsigned short* qf   = (unsigned short*)alloc((size_t)256 * DMODEL * 2);
  unsigned short* kf   = (unsigned short*)alloc((size_t)128 * DMODEL * 2);
  unsigned short* vf   = (unsigned short*)alloc((size_t)128 * DMODEL * 2);
  unsigned short* vbar = (unsigned short*)alloc((size_t)256 * DMODEL * 2);
  int* cols  = (int*)alloc((size_t)SEQ_ * 128 * 4);                             // 1 MB
  int* cnt   = (int*)alloc((size_t)SEQ_ * 4);
  int* tmx   = (int*)alloc((size_t)SEQ_ * 4);
  int* qlist = (int*)alloc(256 * 4);

  hipLaunchKernelGGL(k1_prep, dim3(11264), dim3(256), 0, stream,
                     x, w_qkv, w_out, gamma, beta, ridx,
                     xn, wqT, woT, Wvs, cols, cnt, tmx, qlist);
  hipLaunchKernelGGL(k2_wgemm, dim3(192), dim3(256), 0, stream,
                     woT, Wvs, WvoT, xn, wqT, qlist, qf, kf, vf);
  hipLaunchKernelGGL(k3_xbar, dim3(1060), dim3(256), 0, stream,
                     xn, cols, cnt, tmx, qlist, qf, kf, vf, xbar, vbar);
  hipLaunchKernelGGL(k4_final, dim3(544), dim3(256), 0, stream,
                     xbar, WvoT, vbar, woT, qlist, tmx, x, out);
}

// Round 8
// 174.515 us; speedup vs baseline: 1.3413x; 1.0696x over previous
//
#include <hip/hip_runtime.h>
#include <stdint.h>

typedef __attribute__((ext_vector_type(8))) short shortx8;
typedef __attribute__((ext_vector_type(4))) float floatx4;

static constexpr int SEQ_    = 2048;
static constexpr int DMODEL  = 1024;
static constexpr int HDIM    = 64;
static constexpr int BATCH_  = 2;
static constexpr int NHEADS  = 16;
static constexpr int WINDOW_ = 64;
static constexpr int GTOK    = 4;
static constexpr int RTOK    = 32;
static constexpr int ROWS    = BATCH_ * SEQ_;   // 4096
static constexpr int QKVN    = 3 * DMODEL;      // 3072

__device__ inline unsigned short f2bf(float f) {
  union { float f; unsigned int u; } x; x.f = f;
  unsigned int r = (x.u + 0x7FFFu + ((x.u >> 16) & 1u)) >> 16;
  return (unsigned short)r;
}
__device__ inline float bf2f(unsigned short b) {
  union { unsigned int u; float f; } x; x.u = ((unsigned int)b) << 16;
  return x.f;
}

__device__ inline void gload_lds16(const void* g, void* l) {
  __builtin_amdgcn_global_load_lds(
      (const __attribute__((address_space(1))) void*)g,
      (__attribute__((address_space(3))) void*)l, 16, 0, 0);
}

// ---- shared MFMA GEMM core: 128x64 tile, K=1024, BK=32, 4 waves (2x2) ----
__device__ __forceinline__ void gemm_core_k1024(
    const unsigned short* __restrict__ aSrc0, const unsigned short* __restrict__ aSrc1,
    const unsigned short* __restrict__ bSrc,
    unsigned short* Al, unsigned short* Bl,
    const int wave, const int lane, floatx4 (&acc)[4][2]) {
  const int quad = lane >> 4, l16 = lane & 15;
  const int wm = (wave >> 1) * 64, wn = (wave & 1) * 32;
  unsigned short* AlD0 = Al + (wave * 32) * 32;
  unsigned short* AlD1 = Al + (wave * 32 + 16) * 32;
  unsigned short* BlD  = Bl + (wave * 16) * 32;
  for (int k0 = 0; k0 < 1024; k0 += 32) {
    __syncthreads();
    gload_lds16(aSrc0 + k0, AlD0);
    gload_lds16(aSrc1 + k0, AlD1);
    gload_lds16(bSrc  + k0, BlD);
    __syncthreads();
    shortx8 af[4], bfr[2];
    #pragma unroll
    for (int s = 0; s < 4; s++)
      af[s] = *(const shortx8*)&Al[(wm + s * 16 + l16) * 32 + quad * 8];
    #pragma unroll
    for (int s = 0; s < 2; s++)
      bfr[s] = *(const shortx8*)&Bl[(wn + s * 16 + l16) * 32 + quad * 8];
    #pragma unroll
    for (int sm = 0; sm < 4; sm++)
      #pragma unroll
      for (int sn = 0; sn < 2; sn++)
        acc[sm][sn] = __builtin_amdgcn_mfma_f32_16x16x32_bf16(af[sm], bfr[sn], acc[sm][sn], 0, 0, 0);
  }
}

// =================== K1: LN + weight converts + mask/tier lists ===================
// mask part writes cols segregated: window-cols ascending [0,cw), non-window cols
// descending from slot 127 ([128-cnw,128)). cnt=cw+cnw; cnts2 = cw | (cnw<<16).
__global__ __launch_bounds__(256) void k1_prep(
    const float* __restrict__ x, const float* __restrict__ w_qkv,
    const float* __restrict__ w_out, const float* __restrict__ gamma,
    const float* __restrict__ beta, const int* __restrict__ ridx,
    unsigned short* __restrict__ xn, unsigned short* __restrict__ wqT,
    unsigned short* __restrict__ woT, unsigned short* __restrict__ Wvs,
    int* __restrict__ cols, int* __restrict__ cnt, int* __restrict__ tmx,
    int* __restrict__ cnts2, int* __restrict__ qlist) {
  __shared__ float tile[32][33];
  __shared__ float red[4], red2[4];
  __shared__ int rl[RTOK];
  __shared__ int scw, scnw, stm;
  const int bx = blockIdx.x;
  const int t = threadIdx.x;
  if (bx < 3072) {
    int n0 = (bx % 96) * 32, k0 = (bx / 96) * 32;
    int tx = t & 31, ty = t >> 5;
    #pragma unroll
    for (int r = ty; r < 32; r += 8)
      tile[r][tx] = w_qkv[(size_t)(k0 + r) * QKVN + n0 + tx];
    __syncthreads();
    #pragma unroll
    for (int r = ty; r < 32; r += 8)
      wqT[(size_t)(n0 + r) * DMODEL + k0 + tx] = f2bf(tile[tx][r]);
  } else if (bx < 7168) {
    int row = bx - 3072;
    const float4* xr = (const float4*)(x + (size_t)row * DMODEL);
    float4 v = xr[t];
    float s = v.x + v.y + v.z + v.w;
    #pragma unroll
    for (int o = 32; o > 0; o >>= 1) s += __shfl_xor(s, o);
    int wave = t >> 6, lane = t & 63;
    if (lane == 0) red[wave] = s;
    __syncthreads();
    float mean = (red[0] + red[1] + red[2] + red[3]) * (1.0f / DMODEL);
    float dx = v.x - mean, dy = v.y - mean, dz = v.z - mean, dw = v.w - mean;
    float q = dx*dx + dy*dy + dz*dz + dw*dw;
    #pragma unroll
    for (int o = 32; o > 0; o >>= 1) q += __shfl_xor(q, o);
    if (lane == 0) red2[wave] = q;
    __syncthreads();
    float var = (red2[0] + red2[1] + red2[2] + red2[3]) * (1.0f / DMODEL);
    float rs = rsqrtf(var + 1e-5f);
    float4 g = ((const float4*)gamma)[t];
    float4 bb = ((const float4*)beta)[t];
    ushort4 outv;
    outv.x = f2bf(dx * rs * g.x + bb.x);
    outv.y = f2bf(dy * rs * g.y + bb.y);
    outv.z = f2bf(dz * rs * g.z + bb.z);
    outv.w = f2bf(dw * rs * g.w + bb.w);
    ((ushort4*)(xn + (size_t)row * DMODEL))[t] = outv;
  } else if (bx < 8192) {
    int idx = bx - 7168;
    int n0 = (idx & 31) * 32, k0 = (idx >> 5) * 32;
    int tx = t & 31, ty = t >> 5;
    #pragma unroll
    for (int r = ty; r < 32; r += 8)
      tile[r][tx] = w_out[(size_t)(k0 + r) * DMODEL + n0 + tx];
    __syncthreads();
    #pragma unroll
    for (int r = ty; r < 32; r += 8)
      woT[(size_t)(n0 + r) * DMODEL + k0 + tx] = f2bf(tile[tx][r]);
  } else if (bx < 9216) {
    int idx = bx - 8192;
    int v0 = (idx & 31) * 32, k0 = (idx >> 5) * 32;
    int tx = t & 31, ty = t >> 5;
    #pragma unroll
    for (int r = ty; r < 32; r += 8)
      Wvs[(size_t)(k0 + r) * DMODEL + v0 + tx] =
          f2bf(w_qkv[(size_t)(k0 + r) * QKVN + 2 * DMODEL + v0 + tx]);
  } else {
    const int i = bx - 9216;
    if (t < RTOK) rl[t] = ridx[i * RTOK + t];
    if (t == 0) { scw = 0; scnw = 0; stm = 0; }
    __syncthreads();
    const int wstart = (i - WINDOW_ > 0) ? (i - WINDOW_) : 0;
    const int c = t;
    int j = -1;
    bool valid = false;
    bool iswin = (c < 65);
    if (c < 65) {                       // window candidates (incl diagonal)
      j = i - WINDOW_ + c;
      valid = (j >= 0);
    } else if (c < 73) {                // global cols outside window
      int g = c - 65;
      j = (g < 4) ? g : (SEQ_ - 8 + g);
      valid = (j <= i) && (j < wstart);
    } else if (c < 73 + RTOK) {         // random cols outside window/global, deduped
      int r = c - 73;
      j = rl[r];
      bool dup = false;
      for (int r2 = 0; r2 < r; r2++) dup = dup || (rl[r2] == j);
      valid = (j <= i) && (j < wstart) && !(j < GTOK || j >= SEQ_ - GTOK) && !dup;
    }
    int tier = -1;
    if (valid) {
      int loc = ((i - j) <= WINDOW_) ? 1 : 0;
      int glb = (j < GTOK || j >= SEQ_ - GTOK) ? 1 : 0;
      int rnd = 0;
      for (int r = 0; r < RTOK; r++) rnd |= (rl[r] == j) ? 1 : 0;
      tier = loc + glb + rnd;
      atomicMax(&stm, tier);
    }
    __syncthreads();
    const int tm = stm;
    if (valid && tier == tm) {
      if (iswin) {
        int pos = atomicAdd(&scw, 1);
        cols[i * 128 + pos] = j;
      } else {
        int pos = 127 - atomicAdd(&scnw, 1);
        cols[i * 128 + pos] = j;
      }
    }
    __syncthreads();
    if (t == 0) {
      cnt[i] = scw + scnw;
      tmx[i] = tm;
      cnts2[i] = scw | (scnw << 16);
      if (i < 68 || i >= SEQ_ - 4) {
        int cc = (i < 68) ? i : 68 + (i - (SEQ_ - 4));
        qlist[cc * 2 + 0] = (tm == 3) ? i : -1;
        qlist[cc * 2 + 1] = (tm == 3) ? (SEQ_ + i) : -1;
      }
    }
  }
}

// =================== K2: Wvo weight-GEMM + tier-3 q/k/v gather-GEMMs ===============
__global__ __launch_bounds__(256) void k2_wgemm(
    const unsigned short* __restrict__ woT, const unsigned short* __restrict__ Wvs,
    unsigned short* __restrict__ WvoT, const unsigned short* __restrict__ xn,
    const unsigned short* __restrict__ wqT, const int* __restrict__ qlist,
    unsigned short* __restrict__ qf, unsigned short* __restrict__ kf,
    unsigned short* __restrict__ vf) {
  __shared__ unsigned short Al[128 * 32];
  __shared__ unsigned short Bl[64 * 32];
  const int bx = blockIdx.x, t = threadIdx.x;
  const int wave = t >> 6, lane = t & 63;
  const int lrow = lane >> 2, lkoff = (lane & 3) * 8;
  const int quad = lane >> 4, l16 = lane & 15;
  const int wm = (wave >> 1) * 64, wn = (wave & 1) * 32;
  floatx4 acc[4][2] = {};
  if (bx < 128) {
    const int bm = (bx >> 4) * 128, bn = (bx & 15) * 64;
    const unsigned short* a0 = woT + (size_t)(bm + wave * 32 + lrow) * DMODEL + lkoff;
    const unsigned short* a1 = a0 + 16 * DMODEL;
    const unsigned short* b0 = Wvs + (size_t)(bn + wave * 16 + lrow) * DMODEL + lkoff;
    gemm_core_k1024(a0, a1, b0, Al, Bl, wave, lane, acc);
    #pragma unroll
    for (int sm = 0; sm < 4; sm++)
      #pragma unroll
      for (int sn = 0; sn < 2; sn++)
        #pragma unroll
        for (int r = 0; r < 4; r++) {
          int row = bm + wm + sm * 16 + quad * 4 + r;
          int col = bn + wn + sn * 16 + l16;
          WvoT[(size_t)row * DMODEL + col] = f2bf(acc[sm][sn][r]);
        }
  } else {
    const int idx = bx - 128;
    const int job = idx >> 4, bn = (idx & 15) * 64;
    const int wsel = (job < 2) ? 0 : ((job == 2) ? 1 : 2);
    const unsigned short* BT = wqT + (size_t)wsel * DMODEL * DMODEL;
    unsigned short* dstbuf = (job == 0) ? qf
                           : (job == 1) ? (qf + (size_t)128 * DMODEL)
                           : (job == 2) ? kf : vf;
    int rsrc[2];
    #pragma unroll
    for (int q = 0; q < 2; q++) {
      int m = wave * 32 + q * 16 + lrow;
      int row;
      if (job < 2) {
        int s = job * 128 + m;
        int ql = (s < 144) ? qlist[s] : -1;
        row = (ql < 0) ? 0 : ql;
      } else {
        row = (m < 16) ? ((m >> 3) * SEQ_ + (((m & 7) < 4) ? (m & 7) : (SEQ_ - 8 + (m & 7)))) : 0;
      }
      rsrc[q] = row;
    }
    const unsigned short* a0 = xn + (size_t)rsrc[0] * DMODEL + lkoff;
    const unsigned short* a1 = xn + (size_t)rsrc[1] * DMODEL + lkoff;
    const unsigned short* b0 = BT + (size_t)(bn + wave * 16 + lrow) * DMODEL + lkoff;
    gemm_core_k1024(a0, a1, b0, Al, Bl, wave, lane, acc);
    #pragma unroll
    for (int sm = 0; sm < 4; sm++)
      #pragma unroll
      for (int sn = 0; sn < 2; sn++)
        #pragma unroll
        for (int r = 0; r < 4; r++) {
          int m = wm + sm * 16 + quad * 4 + r;
          int col = bn + wn + sn * 16 + l16;
          dstbuf[(size_t)m * DMODEL + col] = f2bf(acc[sm][sn][r]);
        }
  }
}

// =================== K3: sliding-window xbar + tier-3 softmax ===================
// blocks [0,1024): tile = (batch, 16 rows, 256 dims). Window rows in LDS; per wave a
// sliding fp32 window-sum ws (init ~65 adds, then +row/-row). tm=1 rows: ws + gather of
// cnw non-window cols (slots 128-cnw..127). tm=2 rows: gather cw+cnw listed cols.
// [1024,1060): tier-3 attn fix.
__global__ __launch_bounds__(256) void k3_xbar(
    const unsigned short* __restrict__ xn, const int* __restrict__ cols,
    const int* __restrict__ cnt, const int* __restrict__ tmx,
    const int* __restrict__ cnts2, const int* __restrict__ qlist,
    const unsigned short* __restrict__ qf, const unsigned short* __restrict__ kf,
    const unsigned short* __restrict__ vf,
    unsigned short* __restrict__ xbar, unsigned short* __restrict__ vbar) {
  const int bx = blockIdx.x, t = threadIdx.x;
  const int wave = t >> 6, lane = t & 63;
  if (bx < 1024) {
    __shared__ unsigned short win[80][256];   // rows [i0-64, i0+15] x 256 dims
    const int b = bx >> 9, rest = bx & 511;
    const int i0 = (rest >> 2) * 16, dimbase = (rest & 3) * 256;
    const size_t xnb = (size_t)(b * SEQ_) * DMODEL;
    const int lo = i0 - 64;
    // stage 80 rows, int4/lane: 2 rows per wave-iter (32 lanes x 16B = 512B row)
    {
      const int l5 = lane & 31, rsub = lane >> 5;
      #pragma unroll 5
      for (int it = 0; it < 10; it++) {
        int r = it * 8 + wave * 2 + rsub;
        int gr = lo + r;
        if (gr >= 0)
          *(int4*)&win[r][l5 * 8] =
              *(const int4*)(xn + xnb + (size_t)gr * DMODEL + dimbase + l5 * 8);
      }
    }
    __syncthreads();
    const unsigned short* xnd = xn + xnb + dimbase + lane * 4;
    auto ldcol = [&](int j) -> ushort4 {
      if (j >= lo) return *(const ushort4*)&win[j - lo][lane * 4];
      return *(const ushort4*)(xnd + (size_t)j * DMODEL);
    };
    auto add4 = [](float4& s, ushort4 v) {
      s.x += bf2f(v.x); s.y += bf2f(v.y); s.z += bf2f(v.z); s.w += bf2f(v.w);
    };
    auto sub4 = [](float4& s, ushort4 v) {
      s.x -= bf2f(v.x); s.y -= bf2f(v.y); s.z -= bf2f(v.z); s.w -= bf2f(v.w);
    };
    const int r0 = i0 + wave * 4;
    // init sliding window sum for row r0: rows [max(0,r0-64), r0]
    float4 ws = {0, 0, 0, 0};
    {
      float4 t1 = {0,0,0,0}, t2 = {0,0,0,0}, t3 = {0,0,0,0};
      const int jstart = (r0 - 64 > 0) ? (r0 - 64) : 0;
      const int cn = r0 - jstart + 1;
      const int base = jstart - lo;
      int c = 0;
      for (; c + 4 <= cn; c += 4) {
        ushort4 v0 = *(const ushort4*)&win[base + c][lane * 4];
        ushort4 v1 = *(const ushort4*)&win[base + c + 1][lane * 4];
        ushort4 v2 = *(const ushort4*)&win[base + c + 2][lane * 4];
        ushort4 v3 = *(const ushort4*)&win[base + c + 3][lane * 4];
        add4(ws, v0); add4(t1, v1); add4(t2, v2); add4(t3, v3);
      }
      for (; c < cn; c++) add4(ws, *(const ushort4*)&win[base + c][lane * 4]);
      ws.x += t1.x + t2.x + t3.x; ws.y += t1.y + t2.y + t3.y;
      ws.z += t1.z + t2.z + t3.z; ws.w += t1.w + t2.w + t3.w;
    }
    for (int rr = 0; rr < 4; rr++) {
      const int i = r0 + rr;
      if (rr > 0) {   // slide: add row i, drop row i-65
        add4(ws, *(const ushort4*)&win[i - lo][lane * 4]);
        int dj = i - 65;
        if (dj >= 0) sub4(ws, *(const ushort4*)&win[dj - lo][lane * 4]);
      }
      const int tm = tmx[i];
      ushort4 o;
      if (tm == 3) {
        o.x = o.y = o.z = o.w = 0;
      } else {
        const int c2 = cnts2[i];
        const int cw = c2 & 0xffff, cnw = c2 >> 16;
        const int jr1 = cols[i * 128 + 64 + lane];
        float4 s;
        if (tm == 1) {
          s = ws;
          float4 t1 = {0,0,0,0}, t2 = {0,0,0,0}, t3 = {0,0,0,0};
          const int bb = 64 - cnw;   // jr1 lane of first non-window col
          int c = 0;
          for (; c + 4 <= cnw; c += 4) {
            int j0 = __shfl(jr1, bb + c),     j1 = __shfl(jr1, bb + c + 1);
            int j2 = __shfl(jr1, bb + c + 2), j3 = __shfl(jr1, bb + c + 3);
            ushort4 v0 = ldcol(j0), v1 = ldcol(j1), v2 = ldcol(j2), v3 = ldcol(j3);
            add4(s, v0); add4(t1, v1); add4(t2, v2); add4(t3, v3);
          }
          for (; c < cnw; c++) add4(s, ldcol(__shfl(jr1, bb + c)));
          s.x += t1.x + t2.x + t3.x; s.y += t1.y + t2.y + t3.y;
          s.z += t1.z + t2.z + t3.z; s.w += t1.w + t2.w + t3.w;
        } else {      // tm == 2: gather both segments (small n)
          const int jr0 = cols[i * 128 + lane];
          s.x = s.y = s.z = s.w = 0.f;
          for (int c = 0; c < cw; c++) {
            int j = (c < 64) ? __shfl(jr0, c) : __shfl(jr1, c - 64);
            add4(s, ldcol(j));
          }
          const int bb = 64 - cnw;
          for (int c = 0; c < cnw; c++) add4(s, ldcol(__shfl(jr1, bb + c)));
        }
        const float inv = 1.0f / (float)(cw + cnw);
        o.x = f2bf(s.x * inv); o.y = f2bf(s.y * inv);
        o.z = f2bf(s.z * inv); o.w = f2bf(s.w * inv);
      }
      *(ushort4*)(xbar + (size_t)(b * SEQ_ + i) * DMODEL + dimbase + lane * 4) = o;
    }
  } else {
    const int s = (bx - 1024) * 4 + wave;       // slot in [0,144)
    const int dst = (s < 144) ? qlist[s] : -1;
    if (dst < 0) return;
    const int b = dst >> 11, i = dst & (SEQ_ - 1);
    const int n = cnt[i];                       // tier-3 cols all in lower segment
    int myk = 0;
    if (lane < n) {
      int kj = cols[i * 128 + lane];
      myk = b * 8 + ((kj < 4) ? kj : (kj - (SEQ_ - 8)));
    }
    for (int h = 0; h < NHEADS; h++) {
      float qd = bf2f(qf[(size_t)s * DMODEL + h * HDIM + lane]);
      float w[8];
      float m = -1e30f;
      for (int c = 0; c < n; c++) {
        int ks = __shfl(myk, c);
        float kd = bf2f(kf[(size_t)ks * DMODEL + h * HDIM + lane]);
        float p = qd * kd;
        #pragma unroll
        for (int o = 32; o > 0; o >>= 1) p += __shfl_xor(p, o);
        p *= 0.375f;                    // 3 * (q.k / 8)
        w[c] = p;
        m = fmaxf(m, p);
      }
      float denom = 0.f, acc = 0.f;
      for (int c = 0; c < n; c++) {
        int ks = __shfl(myk, c);
        float e = __expf(w[c] - m);
        denom += e;
        acc += e * bf2f(vf[(size_t)ks * DMODEL + h * HDIM + lane]);
      }
      vbar[(size_t)s * DMODEL + h * HDIM + lane] = f2bf(acc / denom);
    }
  }
}

// =================== K4: main fused GEMM + tier-3 row fixup GEMM ===================
__global__ __launch_bounds__(256) void k4_final(
    const unsigned short* __restrict__ xbar, const unsigned short* __restrict__ WvoT,
    const unsigned short* __restrict__ vbar, const unsigned short* __restrict__ woT,
    const int* __restrict__ qlist, const int* __restrict__ tmx,
    const float* __restrict__ x, float* __restrict__ out) {
  __shared__ unsigned short Al[128 * 32];
  __shared__ unsigned short Bl[64 * 32];
  __shared__ int rowinf[128];
  const int bx = blockIdx.x, t = threadIdx.x;
  const int wave = t >> 6, lane = t & 63;
  const int lrow = lane >> 2, lkoff = (lane & 3) * 8;
  const int quad = lane >> 4, l16 = lane & 15;
  const int wm = (wave >> 1) * 64, wn = (wave & 1) * 32;
  floatx4 acc[4][2] = {};
  if (bx < 512) {
    const int bm = (bx >> 4) * 128, bn = (bx & 15) * 64;
    if (t < 128) rowinf[t] = tmx[(bm + t) & (SEQ_ - 1)];
    const unsigned short* a0 = xbar + (size_t)(bm + wave * 32 + lrow) * DMODEL + lkoff;
    const unsigned short* a1 = a0 + 16 * DMODEL;
    const unsigned short* b0 = WvoT + (size_t)(bn + wave * 16 + lrow) * DMODEL + lkoff;
    gemm_core_k1024(a0, a1, b0, Al, Bl, wave, lane, acc);  // first barrier publishes rowinf
    #pragma unroll
    for (int sm = 0; sm < 4; sm++)
      #pragma unroll
      for (int sn = 0; sn < 2; sn++)
        #pragma unroll
        for (int r = 0; r < 4; r++) {
          int m = wm + sm * 16 + quad * 4 + r;
          if (rowinf[m] != 3) {
            int col = bn + wn + sn * 16 + l16;
            size_t off = (size_t)(bm + m) * DMODEL + col;
            out[off] = acc[sm][sn][r] + x[off];
          }
        }
  } else {
    const int idx = bx - 512;
    const int bm = (idx >> 4) * 128, bn = (idx & 15) * 64;
    if (t < 128) {
      int s = bm + t;
      rowinf[t] = (s < 144) ? qlist[s] : -1;
    }
    const unsigned short* a0 = vbar + (size_t)(bm + wave * 32 + lrow) * DMODEL + lkoff;
    const unsigned short* a1 = a0 + 16 * DMODEL;
    const unsigned short* b0 = woT + (size_t)(bn + wave * 16 + lrow) * DMODEL + lkoff;
    gemm_core_k1024(a0, a1, b0, Al, Bl, wave, lane, acc);
    #pragma unroll
    for (int sm = 0; sm < 4; sm++)
      #pragma unroll
      for (int sn = 0; sn < 2; sn++)
        #pragma unroll
        for (int r = 0; r < 4; r++) {
          int m = wm + sm * 16 + quad * 4 + r;
          int dst = rowinf[m];
          if (dst >= 0) {
            int col = bn + wn + sn * 16 + l16;
            size_t off = (size_t)dst * DMODEL + col;
            out[off] = acc[sm][sn][r] + x[off];
          }
        }
  }
}

extern "C" void kernel_launch(void* const* d_in, const int* in_sizes, int n_in,
                              void* d_out, int out_size, void* d_ws, size_t ws_size,
                              hipStream_t stream) {
  const float* x     = (const float*)d_in[0];
  const float* w_qkv = (const float*)d_in[1];
  const float* w_out = (const float*)d_in[2];
  const float* gamma = (const float*)d_in[3];
  const float* beta  = (const float*)d_in[4];
  const int*   ridx  = (const int*)d_in[5];
  float* out = (float*)d_out;

  char* ws = (char*)d_ws;
  size_t off = 0;
  auto alloc = [&](size_t bytes) {
    char* p = ws + off;
    off = (off + bytes + 255) & ~(size_t)255;
    return p;
  };
  unsigned short* xn   = (unsigned short*)alloc((size_t)ROWS * DMODEL * 2);     // 8 MB
  unsigned short* wqT  = (unsigned short*)alloc((size_t)QKVN * DMODEL * 2);     // 6 MB
  unsigned short* woT  = (unsigned short*)alloc((size_t)DMODEL * DMODEL * 2);   // 2 MB
  unsigned short* Wvs  = (unsigned short*)alloc((size_t)DMODEL * DMODEL * 2);   // 2 MB
  unsigned short* WvoT = (unsigned short*)alloc((size_t)DMODEL * DMODEL * 2);   // 2 MB
  unsigned short* xbar = (unsigned short*)alloc((size_t)ROWS * DMODEL * 2);     // 8 MB
  unsigned short* qf   = (unsigned short*)alloc((size_t)256 * DMODEL * 2);
  unsigned short* kf   = (unsigned short*)alloc((size_t)128 * DMODEL * 2);
  unsigned short* vf   = (unsigned short*)alloc((size_t)128 * DMODEL * 2);
  unsigned short* vbar = (unsigned short*)alloc((size_t)256 * DMODEL * 2);
  int* cols  = (int*)alloc((size_t)SEQ_ * 128 * 4);                             // 1 MB
  int* cnt   = (int*)alloc((size_t)SEQ_ * 4);
  int* tmx   = (int*)alloc((size_t)SEQ_ * 4);
  int* cnts2 = (int*)alloc((size_t)SEQ_ * 4);
  int* qlist = (int*)alloc(256 * 4);

  hipLaunchKernelGGL(k1_prep, dim3(11264), dim3(256), 0, stream,
                     x, w_qkv, w_out, gamma, beta, ridx,
                     xn, wqT, woT, Wvs, cols, cnt, tmx, cnts2, qlist);
  hipLaunchKernelGGL(k2_wgemm, dim3(192), dim3(256), 0, stream,
                     woT, Wvs, WvoT, xn, wqT, qlist, qf, kf, vf);
  hipLaunchKernelGGL(k3_xbar, dim3(1060), dim3(256), 0, stream,
                     xn, cols, cnt, tmx, cnts2, qlist, qf, kf, vf, xbar, vbar);
  hipLaunchKernelGGL(k4_final, dim3(544), dim3(256), 0, stream,
                     xbar, WvoT, vbar, woT, qlist, tmx, x, out);
}

// Round 9
// 168.381 us; speedup vs baseline: 1.3902x; 1.0364x over previous
//
#include <hip/hip_runtime.h>
#include <stdint.h>

typedef __attribute__((ext_vector_type(8))) short shortx8;
typedef __attribute__((ext_vector_type(4))) float floatx4;

static constexpr int SEQ_    = 2048;
static constexpr int DMODEL  = 1024;
static constexpr int HDIM    = 64;
static constexpr int BATCH_  = 2;
static constexpr int NHEADS  = 16;
static constexpr int WINDOW_ = 64;
static constexpr int GTOK    = 4;
static constexpr int RTOK    = 32;
static constexpr int ROWS    = BATCH_ * SEQ_;   // 4096
static constexpr int QKVN    = 3 * DMODEL;      // 3072

__device__ inline unsigned short f2bf(float f) {
  union { float f; unsigned int u; } x; x.f = f;
  unsigned int r = (x.u + 0x7FFFu + ((x.u >> 16) & 1u)) >> 16;
  return (unsigned short)r;
}
__device__ inline float bf2f(unsigned short b) {
  union { unsigned int u; float f; } x; x.u = ((unsigned int)b) << 16;
  return x.f;
}

__device__ inline void gload_lds16(const void* g, void* l) {
  __builtin_amdgcn_global_load_lds(
      (const __attribute__((address_space(1))) void*)g,
      (__attribute__((address_space(3))) void*)l, 16, 0, 0);
}

// ---- shared MFMA GEMM core: 128x64 tile, K=1024, BK=32, 4 waves (2x2) ----
__device__ __forceinline__ void gemm_core_k1024(
    const unsigned short* __restrict__ aSrc0, const unsigned short* __restrict__ aSrc1,
    const unsigned short* __restrict__ bSrc,
    unsigned short* Al, unsigned short* Bl,
    const int wave, const int lane, floatx4 (&acc)[4][2]) {
  const int quad = lane >> 4, l16 = lane & 15;
  const int wm = (wave >> 1) * 64, wn = (wave & 1) * 32;
  unsigned short* AlD0 = Al + (wave * 32) * 32;
  unsigned short* AlD1 = Al + (wave * 32 + 16) * 32;
  unsigned short* BlD  = Bl + (wave * 16) * 32;
  for (int k0 = 0; k0 < 1024; k0 += 32) {
    __syncthreads();
    gload_lds16(aSrc0 + k0, AlD0);
    gload_lds16(aSrc1 + k0, AlD1);
    gload_lds16(bSrc  + k0, BlD);
    __syncthreads();
    shortx8 af[4], bfr[2];
    #pragma unroll
    for (int s = 0; s < 4; s++)
      af[s] = *(const shortx8*)&Al[(wm + s * 16 + l16) * 32 + quad * 8];
    #pragma unroll
    for (int s = 0; s < 2; s++)
      bfr[s] = *(const shortx8*)&Bl[(wn + s * 16 + l16) * 32 + quad * 8];
    #pragma unroll
    for (int sm = 0; sm < 4; sm++)
      #pragma unroll
      for (int sn = 0; sn < 2; sn++)
        acc[sm][sn] = __builtin_amdgcn_mfma_f32_16x16x32_bf16(af[sm], bfr[sn], acc[sm][sn], 0, 0, 0);
  }
}

// =================== K1: LN + weight converts + mask/tier lists ===================
// mask part writes cols segregated: window-cols ascending [0,cw), non-window cols
// descending from slot 127 ([128-cnw,128)). cnt=cw+cnw; cnts2 = cw | (cnw<<16).
__global__ __launch_bounds__(256) void k1_prep(
    const float* __restrict__ x, const float* __restrict__ w_qkv,
    const float* __restrict__ w_out, const float* __restrict__ gamma,
    const float* __restrict__ beta, const int* __restrict__ ridx,
    unsigned short* __restrict__ xn, unsigned short* __restrict__ wqT,
    unsigned short* __restrict__ woT, unsigned short* __restrict__ Wvs,
    int* __restrict__ cols, int* __restrict__ cnt, int* __restrict__ tmx,
    int* __restrict__ cnts2, int* __restrict__ qlist) {
  __shared__ float tile[32][33];
  __shared__ float red[4], red2[4];
  __shared__ int rl[RTOK];
  __shared__ int scw, scnw, stm;
  const int bx = blockIdx.x;
  const int t = threadIdx.x;
  if (bx < 3072) {
    int n0 = (bx % 96) * 32, k0 = (bx / 96) * 32;
    int tx = t & 31, ty = t >> 5;
    #pragma unroll
    for (int r = ty; r < 32; r += 8)
      tile[r][tx] = w_qkv[(size_t)(k0 + r) * QKVN + n0 + tx];
    __syncthreads();
    #pragma unroll
    for (int r = ty; r < 32; r += 8)
      wqT[(size_t)(n0 + r) * DMODEL + k0 + tx] = f2bf(tile[tx][r]);
  } else if (bx < 7168) {
    int row = bx - 3072;
    const float4* xr = (const float4*)(x + (size_t)row * DMODEL);
    float4 v = xr[t];
    float s = v.x + v.y + v.z + v.w;
    #pragma unroll
    for (int o = 32; o > 0; o >>= 1) s += __shfl_xor(s, o);
    int wave = t >> 6, lane = t & 63;
    if (lane == 0) red[wave] = s;
    __syncthreads();
    float mean = (red[0] + red[1] + red[2] + red[3]) * (1.0f / DMODEL);
    float dx = v.x - mean, dy = v.y - mean, dz = v.z - mean, dw = v.w - mean;
    float q = dx*dx + dy*dy + dz*dz + dw*dw;
    #pragma unroll
    for (int o = 32; o > 0; o >>= 1) q += __shfl_xor(q, o);
    if (lane == 0) red2[wave] = q;
    __syncthreads();
    float var = (red2[0] + red2[1] + red2[2] + red2[3]) * (1.0f / DMODEL);
    float rs = rsqrtf(var + 1e-5f);
    float4 g = ((const float4*)gamma)[t];
    float4 bb = ((const float4*)beta)[t];
    ushort4 outv;
    outv.x = f2bf(dx * rs * g.x + bb.x);
    outv.y = f2bf(dy * rs * g.y + bb.y);
    outv.z = f2bf(dz * rs * g.z + bb.z);
    outv.w = f2bf(dw * rs * g.w + bb.w);
    ((ushort4*)(xn + (size_t)row * DMODEL))[t] = outv;
  } else if (bx < 8192) {
    int idx = bx - 7168;
    int n0 = (idx & 31) * 32, k0 = (idx >> 5) * 32;
    int tx = t & 31, ty = t >> 5;
    #pragma unroll
    for (int r = ty; r < 32; r += 8)
      tile[r][tx] = w_out[(size_t)(k0 + r) * DMODEL + n0 + tx];
    __syncthreads();
    #pragma unroll
    for (int r = ty; r < 32; r += 8)
      woT[(size_t)(n0 + r) * DMODEL + k0 + tx] = f2bf(tile[tx][r]);
  } else if (bx < 9216) {
    int idx = bx - 8192;
    int v0 = (idx & 31) * 32, k0 = (idx >> 5) * 32;
    int tx = t & 31, ty = t >> 5;
    #pragma unroll
    for (int r = ty; r < 32; r += 8)
      Wvs[(size_t)(k0 + r) * DMODEL + v0 + tx] =
          f2bf(w_qkv[(size_t)(k0 + r) * QKVN + 2 * DMODEL + v0 + tx]);
  } else {
    const int i = bx - 9216;
    if (t < RTOK) rl[t] = ridx[i * RTOK + t];
    if (t == 0) { scw = 0; scnw = 0; stm = 0; }
    __syncthreads();
    const int wstart = (i - WINDOW_ > 0) ? (i - WINDOW_) : 0;
    const int c = t;
    int j = -1;
    bool valid = false;
    bool iswin = (c < 65);
    if (c < 65) {                       // window candidates (incl diagonal)
      j = i - WINDOW_ + c;
      valid = (j >= 0);
    } else if (c < 73) {                // global cols outside window
      int g = c - 65;
      j = (g < 4) ? g : (SEQ_ - 8 + g);
      valid = (j <= i) && (j < wstart);
    } else if (c < 73 + RTOK) {         // random cols outside window/global, deduped
      int r = c - 73;
      j = rl[r];
      bool dup = false;
      for (int r2 = 0; r2 < r; r2++) dup = dup || (rl[r2] == j);
      valid = (j <= i) && (j < wstart) && !(j < GTOK || j >= SEQ_ - GTOK) && !dup;
    }
    int tier = -1;
    if (valid) {
      int loc = ((i - j) <= WINDOW_) ? 1 : 0;
      int glb = (j < GTOK || j >= SEQ_ - GTOK) ? 1 : 0;
      int rnd = 0;
      for (int r = 0; r < RTOK; r++) rnd |= (rl[r] == j) ? 1 : 0;
      tier = loc + glb + rnd;
      atomicMax(&stm, tier);
    }
    __syncthreads();
    const int tm = stm;
    if (valid && tier == tm) {
      if (iswin) {
        int pos = atomicAdd(&scw, 1);
        cols[i * 128 + pos] = j;
      } else {
        int pos = 127 - atomicAdd(&scnw, 1);
        cols[i * 128 + pos] = j;
      }
    }
    __syncthreads();
    if (t == 0) {
      cnt[i] = scw + scnw;
      tmx[i] = tm;
      cnts2[i] = scw | (scnw << 16);
      if (i < 68 || i >= SEQ_ - 4) {
        int cc = (i < 68) ? i : 68 + (i - (SEQ_ - 4));
        qlist[cc * 2 + 0] = (tm == 3) ? i : -1;
        qlist[cc * 2 + 1] = (tm == 3) ? (SEQ_ + i) : -1;
      }
    }
  }
}

// =================== K2: Wvo weight-GEMM + tier-3 q/k/v gather-GEMMs ===============
__global__ __launch_bounds__(256) void k2_wgemm(
    const unsigned short* __restrict__ woT, const unsigned short* __restrict__ Wvs,
    unsigned short* __restrict__ WvoT, const unsigned short* __restrict__ xn,
    const unsigned short* __restrict__ wqT, const int* __restrict__ qlist,
    unsigned short* __restrict__ qf, unsigned short* __restrict__ kf,
    unsigned short* __restrict__ vf) {
  __shared__ unsigned short Al[128 * 32];
  __shared__ unsigned short Bl[64 * 32];
  const int bx = blockIdx.x, t = threadIdx.x;
  const int wave = t >> 6, lane = t & 63;
  const int lrow = lane >> 2, lkoff = (lane & 3) * 8;
  const int quad = lane >> 4, l16 = lane & 15;
  const int wm = (wave >> 1) * 64, wn = (wave & 1) * 32;
  floatx4 acc[4][2] = {};
  if (bx < 128) {
    const int bm = (bx >> 4) * 128, bn = (bx & 15) * 64;
    const unsigned short* a0 = woT + (size_t)(bm + wave * 32 + lrow) * DMODEL + lkoff;
    const unsigned short* a1 = a0 + 16 * DMODEL;
    const unsigned short* b0 = Wvs + (size_t)(bn + wave * 16 + lrow) * DMODEL + lkoff;
    gemm_core_k1024(a0, a1, b0, Al, Bl, wave, lane, acc);
    #pragma unroll
    for (int sm = 0; sm < 4; sm++)
      #pragma unroll
      for (int sn = 0; sn < 2; sn++)
        #pragma unroll
        for (int r = 0; r < 4; r++) {
          int row = bm + wm + sm * 16 + quad * 4 + r;
          int col = bn + wn + sn * 16 + l16;
          WvoT[(size_t)row * DMODEL + col] = f2bf(acc[sm][sn][r]);
        }
  } else {
    const int idx = bx - 128;
    const int job = idx >> 4, bn = (idx & 15) * 64;
    const int wsel = (job < 2) ? 0 : ((job == 2) ? 1 : 2);
    const unsigned short* BT = wqT + (size_t)wsel * DMODEL * DMODEL;
    unsigned short* dstbuf = (job == 0) ? qf
                           : (job == 1) ? (qf + (size_t)128 * DMODEL)
                           : (job == 2) ? kf : vf;
    int rsrc[2];
    #pragma unroll
    for (int q = 0; q < 2; q++) {
      int m = wave * 32 + q * 16 + lrow;
      int row;
      if (job < 2) {
        int s = job * 128 + m;
        int ql = (s < 144) ? qlist[s] : -1;
        row = (ql < 0) ? 0 : ql;
      } else {
        row = (m < 16) ? ((m >> 3) * SEQ_ + (((m & 7) < 4) ? (m & 7) : (SEQ_ - 8 + (m & 7)))) : 0;
      }
      rsrc[q] = row;
    }
    const unsigned short* a0 = xn + (size_t)rsrc[0] * DMODEL + lkoff;
    const unsigned short* a1 = xn + (size_t)rsrc[1] * DMODEL + lkoff;
    const unsigned short* b0 = BT + (size_t)(bn + wave * 16 + lrow) * DMODEL + lkoff;
    gemm_core_k1024(a0, a1, b0, Al, Bl, wave, lane, acc);
    #pragma unroll
    for (int sm = 0; sm < 4; sm++)
      #pragma unroll
      for (int sn = 0; sn < 2; sn++)
        #pragma unroll
        for (int r = 0; r < 4; r++) {
          int m = wm + sm * 16 + quad * 4 + r;
          int col = bn + wn + sn * 16 + l16;
          dstbuf[(size_t)m * DMODEL + col] = f2bf(acc[sm][sn][r]);
        }
  }
}

// =================== K3: sliding-window xbar + tier-3 softmax ===================
// blocks [0,1024): tile = (batch, 16 rows, 256 dims). Window rows in LDS feed a
// sliding fp32 window-sum; all listed-col gathers go straight to global (L3-resident,
// coalesced 512B/wave segments), branchless, 8-deep ILP. Per-wave metadata for the
// 4 rows is preloaded before the row loop (no serial chain re-entry).
// [1024,1060): tier-3 attn fix.
__global__ __launch_bounds__(256) void k3_xbar(
    const unsigned short* __restrict__ xn, const int* __restrict__ cols,
    const int* __restrict__ cnt, const int* __restrict__ tmx,
    const int* __restrict__ cnts2, const int* __restrict__ qlist,
    const unsigned short* __restrict__ qf, const unsigned short* __restrict__ kf,
    const unsigned short* __restrict__ vf,
    unsigned short* __restrict__ xbar, unsigned short* __restrict__ vbar) {
  const int bx = blockIdx.x, t = threadIdx.x;
  const int wave = t >> 6, lane = t & 63;
  if (bx < 1024) {
    __shared__ unsigned short win[80][256];   // rows [i0-64, i0+15] x 256 dims
    const int b = bx >> 9, rest = bx & 511;
    const int i0 = (rest >> 2) * 16, dimbase = (rest & 3) * 256;
    const size_t xnb = (size_t)(b * SEQ_) * DMODEL;
    const int lo = i0 - 64;
    const int r0 = i0 + wave * 4;
    // ---- preload metadata for this wave's 4 rows (coalesced, before chains) ----
    int tm_[4], cw_[4], cnw_[4], jr0_[4], jr1_[4];
    #pragma unroll
    for (int rr = 0; rr < 4; rr++) {
      const int i = r0 + rr;
      tm_[rr] = tmx[i];
      int c2 = cnts2[i];
      cw_[rr] = c2 & 0xffff; cnw_[rr] = c2 >> 16;
      jr0_[rr] = cols[i * 128 + lane];
      jr1_[rr] = cols[i * 128 + 64 + lane];
    }
    // ---- stage 80 window rows, int4/lane: 2 rows per wave-iter ----
    {
      const int l5 = lane & 31, rsub = lane >> 5;
      #pragma unroll 5
      for (int it = 0; it < 10; it++) {
        int r = it * 8 + wave * 2 + rsub;
        int gr = lo + r;
        if (gr >= 0)
          *(int4*)&win[r][l5 * 8] =
              *(const int4*)(xn + xnb + (size_t)gr * DMODEL + dimbase + l5 * 8);
      }
    }
    __syncthreads();
    const unsigned short* xnd = xn + xnb + dimbase + lane * 4;
    auto add4 = [](float4& s, ushort4 v) {
      s.x += bf2f(v.x); s.y += bf2f(v.y); s.z += bf2f(v.z); s.w += bf2f(v.w);
    };
    auto sub4 = [](float4& s, ushort4 v) {
      s.x -= bf2f(v.x); s.y -= bf2f(v.y); s.z -= bf2f(v.z); s.w -= bf2f(v.w);
    };
    // ---- init sliding window sum for row r0: rows [max(0,r0-64), r0] ----
    float4 ws = {0, 0, 0, 0};
    {
      float4 t1 = {0,0,0,0}, t2 = {0,0,0,0}, t3 = {0,0,0,0};
      const int jstart = (r0 - 64 > 0) ? (r0 - 64) : 0;
      const int cn = r0 - jstart + 1;
      const int base = jstart - lo;
      int c = 0;
      for (; c + 4 <= cn; c += 4) {
        ushort4 v0 = *(const ushort4*)&win[base + c][lane * 4];
        ushort4 v1 = *(const ushort4*)&win[base + c + 1][lane * 4];
        ushort4 v2 = *(const ushort4*)&win[base + c + 2][lane * 4];
        ushort4 v3 = *(const ushort4*)&win[base + c + 3][lane * 4];
        add4(ws, v0); add4(t1, v1); add4(t2, v2); add4(t3, v3);
      }
      for (; c < cn; c++) add4(ws, *(const ushort4*)&win[base + c][lane * 4]);
      ws.x += t1.x + t2.x + t3.x; ws.y += t1.y + t2.y + t3.y;
      ws.z += t1.z + t2.z + t3.z; ws.w += t1.w + t2.w + t3.w;
    }
    for (int rr = 0; rr < 4; rr++) {
      const int i = r0 + rr;
      if (rr > 0) {   // slide: add row i, drop row i-65
        add4(ws, *(const ushort4*)&win[i - lo][lane * 4]);
        int dj = i - 65;
        if (dj >= 0) sub4(ws, *(const ushort4*)&win[dj - lo][lane * 4]);
      }
      const int tm = tm_[rr];
      ushort4 o;
      if (tm == 3) {
        o.x = o.y = o.z = o.w = 0;
      } else {
        const int cw = cw_[rr], cnw = cnw_[rr];
        const int jr1 = jr1_[rr];
        float4 s;
        if (tm == 1) {
          // s = ws + gather of cnw non-window cols; branchless global, 8-deep ILP
          s = ws;
          float4 t1 = {0,0,0,0}, t2 = {0,0,0,0}, t3 = {0,0,0,0};
          const int bb = 64 - cnw;
          int c = 0;
          for (; c + 8 <= cnw; c += 8) {
            ushort4 v0 = *(const ushort4*)(xnd + (size_t)__shfl(jr1, bb + c)     * DMODEL);
            ushort4 v1 = *(const ushort4*)(xnd + (size_t)__shfl(jr1, bb + c + 1) * DMODEL);
            ushort4 v2 = *(const ushort4*)(xnd + (size_t)__shfl(jr1, bb + c + 2) * DMODEL);
            ushort4 v3 = *(const ushort4*)(xnd + (size_t)__shfl(jr1, bb + c + 3) * DMODEL);
            ushort4 v4 = *(const ushort4*)(xnd + (size_t)__shfl(jr1, bb + c + 4) * DMODEL);
            ushort4 v5 = *(const ushort4*)(xnd + (size_t)__shfl(jr1, bb + c + 5) * DMODEL);
            ushort4 v6 = *(const ushort4*)(xnd + (size_t)__shfl(jr1, bb + c + 6) * DMODEL);
            ushort4 v7 = *(const ushort4*)(xnd + (size_t)__shfl(jr1, bb + c + 7) * DMODEL);
            add4(s, v0); add4(t1, v1); add4(t2, v2); add4(t3, v3);
            add4(s, v4); add4(t1, v5); add4(t2, v6); add4(t3, v7);
          }
          if (c + 4 <= cnw) {
            ushort4 v0 = *(const ushort4*)(xnd + (size_t)__shfl(jr1, bb + c)     * DMODEL);
            ushort4 v1 = *(const ushort4*)(xnd + (size_t)__shfl(jr1, bb + c + 1) * DMODEL);
            ushort4 v2 = *(const ushort4*)(xnd + (size_t)__shfl(jr1, bb + c + 2) * DMODEL);
            ushort4 v3 = *(const ushort4*)(xnd + (size_t)__shfl(jr1, bb + c + 3) * DMODEL);
            add4(s, v0); add4(t1, v1); add4(t2, v2); add4(t3, v3);
            c += 4;
          }
          for (; c < cnw; c++)
            add4(s, *(const ushort4*)(xnd + (size_t)__shfl(jr1, bb + c) * DMODEL));
          s.x += t1.x + t2.x + t3.x; s.y += t1.y + t2.y + t3.y;
          s.z += t1.z + t2.z + t3.z; s.w += t1.w + t2.w + t3.w;
        } else {      // tm == 2: small n, branchless global gathers
          const int jr0 = jr0_[rr];
          s.x = s.y = s.z = s.w = 0.f;
          for (int c = 0; c < cw; c++) {
            int j = (c < 64) ? __shfl(jr0, c) : __shfl(jr1, c - 64);
            add4(s, *(const ushort4*)(xnd + (size_t)j * DMODEL));
          }
          const int bb = 64 - cnw;
          for (int c = 0; c < cnw; c++)
            add4(s, *(const ushort4*)(xnd + (size_t)__shfl(jr1, bb + c) * DMODEL));
        }
        const float inv = 1.0f / (float)(cw + cnw);
        o.x = f2bf(s.x * inv); o.y = f2bf(s.y * inv);
        o.z = f2bf(s.z * inv); o.w = f2bf(s.w * inv);
      }
      *(ushort4*)(xbar + (size_t)(b * SEQ_ + i) * DMODEL + dimbase + lane * 4) = o;
    }
  } else {
    const int s = (bx - 1024) * 4 + wave;       // slot in [0,144)
    const int dst = (s < 144) ? qlist[s] : -1;
    if (dst < 0) return;
    const int b = dst >> 11, i = dst & (SEQ_ - 1);
    const int n = cnt[i];                       // tier-3 cols all in lower segment
    int myk = 0;
    if (lane < n) {
      int kj = cols[i * 128 + lane];
      myk = b * 8 + ((kj < 4) ? kj : (kj - (SEQ_ - 8)));
    }
    for (int h = 0; h < NHEADS; h++) {
      float qd = bf2f(qf[(size_t)s * DMODEL + h * HDIM + lane]);
      float w[8];
      float m = -1e30f;
      for (int c = 0; c < n; c++) {
        int ks = __shfl(myk, c);
        float kd = bf2f(kf[(size_t)ks * DMODEL + h * HDIM + lane]);
        float p = qd * kd;
        #pragma unroll
        for (int o = 32; o > 0; o >>= 1) p += __shfl_xor(p, o);
        p *= 0.375f;                    // 3 * (q.k / 8)
        w[c] = p;
        m = fmaxf(m, p);
      }
      float denom = 0.f, acc = 0.f;
      for (int c = 0; c < n; c++) {
        int ks = __shfl(myk, c);
        float e = __expf(w[c] - m);
        denom += e;
        acc += e * bf2f(vf[(size_t)ks * DMODEL + h * HDIM + lane]);
      }
      vbar[(size_t)s * DMODEL + h * HDIM + lane] = f2bf(acc / denom);
    }
  }
}

// =================== K4: main fused GEMM + tier-3 row fixup GEMM ===================
__global__ __launch_bounds__(256) void k4_final(
    const unsigned short* __restrict__ xbar, const unsigned short* __restrict__ WvoT,
    const unsigned short* __restrict__ vbar, const unsigned short* __restrict__ woT,
    const int* __restrict__ qlist, const int* __restrict__ tmx,
    const float* __restrict__ x, float* __restrict__ out) {
  __shared__ unsigned short Al[128 * 32];
  __shared__ unsigned short Bl[64 * 32];
  __shared__ int rowinf[128];
  const int bx = blockIdx.x, t = threadIdx.x;
  const int wave = t >> 6, lane = t & 63;
  const int lrow = lane >> 2, lkoff = (lane & 3) * 8;
  const int quad = lane >> 4, l16 = lane & 15;
  const int wm = (wave >> 1) * 64, wn = (wave & 1) * 32;
  floatx4 acc[4][2] = {};
  if (bx < 512) {
    const int bm = (bx >> 4) * 128, bn = (bx & 15) * 64;
    if (t < 128) rowinf[t] = tmx[(bm + t) & (SEQ_ - 1)];
    const unsigned short* a0 = xbar + (size_t)(bm + wave * 32 + lrow) * DMODEL + lkoff;
    const unsigned short* a1 = a0 + 16 * DMODEL;
    const unsigned short* b0 = WvoT + (size_t)(bn + wave * 16 + lrow) * DMODEL + lkoff;
    gemm_core_k1024(a0, a1, b0, Al, Bl, wave, lane, acc);  // first barrier publishes rowinf
    #pragma unroll
    for (int sm = 0; sm < 4; sm++)
      #pragma unroll
      for (int sn = 0; sn < 2; sn++)
        #pragma unroll
        for (int r = 0; r < 4; r++) {
          int m = wm + sm * 16 + quad * 4 + r;
          if (rowinf[m] != 3) {
            int col = bn + wn + sn * 16 + l16;
            size_t off = (size_t)(bm + m) * DMODEL + col;
            out[off] = acc[sm][sn][r] + x[off];
          }
        }
  } else {
    const int idx = bx - 512;
    const int bm = (idx >> 4) * 128, bn = (idx & 15) * 64;
    if (t < 128) {
      int s = bm + t;
      rowinf[t] = (s < 144) ? qlist[s] : -1;
    }
    const unsigned short* a0 = vbar + (size_t)(bm + wave * 32 + lrow) * DMODEL + lkoff;
    const unsigned short* a1 = a0 + 16 * DMODEL;
    const unsigned short* b0 = woT + (size_t)(bn + wave * 16 + lrow) * DMODEL + lkoff;
    gemm_core_k1024(a0, a1, b0, Al, Bl, wave, lane, acc);
    #pragma unroll
    for (int sm = 0; sm < 4; sm++)
      #pragma unroll
      for (int sn = 0; sn < 2; sn++)
        #pragma unroll
        for (int r = 0; r < 4; r++) {
          int m = wm + sm * 16 + quad * 4 + r;
          int dst = rowinf[m];
          if (dst >= 0) {
            int col = bn + wn + sn * 16 + l16;
            size_t off = (size_t)dst * DMODEL + col;
            out[off] = acc[sm][sn][r] + x[off];
          }
        }
  }
}

extern "C" void kernel_launch(void* const* d_in, const int* in_sizes, int n_in,
                              void* d_out, int out_size, void* d_ws, size_t ws_size,
                              hipStream_t stream) {
  const float* x     = (const float*)d_in[0];
  const float* w_qkv = (const float*)d_in[1];
  const float* w_out = (const float*)d_in[2];
  const float* gamma = (const float*)d_in[3];
  const float* beta  = (const float*)d_in[4];
  const int*   ridx  = (const int*)d_in[5];
  float* out = (float*)d_out;

  char* ws = (char*)d_ws;
  size_t off = 0;
  auto alloc = [&](size_t bytes) {
    char* p = ws + off;
    off = (off + bytes + 255) & ~(size_t)255;
    return p;
  };
  unsigned short* xn   = (unsigned short*)alloc((size_t)ROWS * DMODEL * 2);     // 8 MB
  unsigned short* wqT  = (unsigned short*)alloc((size_t)QKVN * DMODEL * 2);     // 6 MB
  unsigned short* woT  = (unsigned short*)alloc((size_t)DMODEL * DMODEL * 2);   // 2 MB
  unsigned short* Wvs  = (unsigned short*)alloc((size_t)DMODEL * DMODEL * 2);   // 2 MB
  unsigned short* WvoT = (unsigned short*)alloc((size_t)DMODEL * DMODEL * 2);   // 2 MB
  unsigned short* xbar = (unsigned short*)alloc((size_t)ROWS * DMODEL * 2);     // 8 MB
  unsigned short* qf   = (unsigned short*)alloc((size_t)256 * DMODEL * 2);
  unsigned short* kf   = (unsigned short*)alloc((size_t)128 * DMODEL * 2);
  unsigned short* vf   = (unsigned short*)alloc((size_t)128 * DMODEL * 2);
  unsigned short* vbar = (unsigned short*)alloc((size_t)256 * DMODEL * 2);
  int* cols  = (int*)alloc((size_t)SEQ_ * 128 * 4);                             // 1 MB
  int* cnt   = (int*)alloc((size_t)SEQ_ * 4);
  int* tmx   = (int*)alloc((size_t)SEQ_ * 4);
  int* cnts2 = (int*)alloc((size_t)SEQ_ * 4);
  int* qlist = (int*)alloc(256 * 4);

  hipLaunchKernelGGL(k1_prep, dim3(11264), dim3(256), 0, stream,
                     x, w_qkv, w_out, gamma, beta, ridx,
                     xn, wqT, woT, Wvs, cols, cnt, tmx, cnts2, qlist);
  hipLaunchKernelGGL(k2_wgemm, dim3(192), dim3(256), 0, stream,
                     woT, Wvs, WvoT, xn, wqT, qlist, qf, kf, vf);
  hipLaunchKernelGGL(k3_xbar, dim3(1060), dim3(256), 0, stream,
                     xn, cols, cnt, tmx, cnts2, qlist, qf, kf, vf, xbar, vbar);
  hipLaunchKernelGGL(k4_final, dim3(544), dim3(256), 0, stream,
                     xbar, WvoT, vbar, woT, qlist, tmx, x, out);
}